// Round 16
// baseline (1422.466 us; speedup 1.0000x reference)
//
#include <hip/hip_runtime.h>
#include <hip/hip_bf16.h>

// ViT transformer block: B=32 S=577 D=768 H=12 d=64 MLP=3072, f32 in/out.
// R16: GEMM1 -> 256x256 single-buffer drain (64KB LDS keeps 2 blk/CU; 64
//      MFMA/wave/K-tile doubles drain amortization; AI 66 F/B). GEMM2 back
//      to gemm2b (R10 winner). R15's 64-row tile was BW-bound (FETCH 3.6x).
//      Attention/QKV/LN = R14 (464us baseline).

#define kB   32
#define kS   577
#define kD   768
#define kH   12
#define kd   64
#define kMLP 3072
#define kTOK (kB * kS)   // 18464
#define kMPAD 18688      // 73 * 256 = 146 * 128

typedef short short8 __attribute__((ext_vector_type(8)));
typedef short short4v __attribute__((ext_vector_type(4)));
typedef float f32x4 __attribute__((ext_vector_type(4)));
typedef float f32x16 __attribute__((ext_vector_type(16)));
typedef unsigned u32x4 __attribute__((ext_vector_type(4)));
typedef __bf16 bf16x8 __attribute__((ext_vector_type(8)));

__device__ inline short f2bf(float f) {
  unsigned u = __float_as_uint(f);
  unsigned r = (u + 0x7FFFu + ((u >> 16) & 1u)) >> 16;
  return (short)r;
}

__device__ inline f32x4 mfma16(short8 a, short8 b, f32x4 c) {
  return __builtin_amdgcn_mfma_f32_16x16x32_bf16(
      __builtin_bit_cast(bf16x8, a), __builtin_bit_cast(bf16x8, b), c, 0, 0, 0);
}

__device__ inline f32x16 mfma32(short8 a, short8 b, f32x16 c) {
  return __builtin_amdgcn_mfma_f32_32x32x16_bf16(
      __builtin_bit_cast(bf16x8, a), __builtin_bit_cast(bf16x8, b), c, 0, 0, 0);
}

__device__ inline void load_lds16(const short* g, short* l) {
  __builtin_amdgcn_global_load_lds(
      (__attribute__((address_space(1))) void*)(g),
      (__attribute__((address_space(3))) void*)(l), 16, 0, 0);
}

__device__ inline unsigned cvtpk(float lo, float hi) {
  unsigned r;
  asm("v_cvt_pk_bf16_f32 %0, %1, %2" : "=v"(r) : "v"(lo), "v"(hi));
  return r;
}

__device__ inline void pl32(unsigned &a, unsigned &b) {
  typedef int int2v __attribute__((ext_vector_type(2)));
  int2v r = __builtin_amdgcn_permlane32_swap((int)a, (int)b, false, false);
  a = (unsigned)r[0];
  b = (unsigned)r[1];
}

// NaN-safe tanh-GELU (max dev from exact erf-GELU ~4e-4)
__device__ inline float gelu_f(float x) {
  float u = x * x;
  float z = x * fmaf(0.0713548162f, u, 1.5957691216f);
  float e = __expf(z);
  return x - x / (e + 1.0f);
}

// ------- LayerNorm, wave-per-row: 4 rows/block, shuffle-only reduce -------
__global__ __launch_bounds__(256) void ln_kernel(const float* __restrict__ x,
                                                 const float* __restrict__ g,
                                                 const float* __restrict__ b,
                                                 short* __restrict__ out) {
  int row = blockIdx.x * 4 + (threadIdx.x >> 6);
  int l = threadIdx.x & 63;
  const float* xr = x + (size_t)row * kD + l * 12;
  f32x4 v0 = *(const f32x4*)(xr);
  f32x4 v1 = *(const f32x4*)(xr + 4);
  f32x4 v2 = *(const f32x4*)(xr + 8);
  float s = 0.f, ss = 0.f;
#pragma unroll
  for (int j = 0; j < 4; j++) {
    s += v0[j] + v1[j] + v2[j];
    ss += v0[j] * v0[j] + v1[j] * v1[j] + v2[j] * v2[j];
  }
#pragma unroll
  for (int off = 1; off < 64; off <<= 1) {
    s += __shfl_xor(s, off, 64);
    ss += __shfl_xor(ss, off, 64);
  }
  float mean = s * (1.f / kD);
  float var = ss * (1.f / kD) - mean * mean;
  float rstd = rsqrtf(var + 1e-5f);
  const float* gr = g + l * 12;
  const float* br = b + l * 12;
  f32x4 g0 = *(const f32x4*)(gr),     g1 = *(const f32x4*)(gr + 4),
        g2 = *(const f32x4*)(gr + 8);
  f32x4 b0 = *(const f32x4*)(br),     b1 = *(const f32x4*)(br + 4),
        b2 = *(const f32x4*)(br + 8);
  short4v r0, r1, r2;
#pragma unroll
  for (int j = 0; j < 4; j++) {
    r0[j] = f2bf((v0[j] - mean) * rstd * g0[j] + b0[j]);
    r1[j] = f2bf((v1[j] - mean) * rstd * g1[j] + b1[j]);
    r2[j] = f2bf((v2[j] - mean) * rstd * g2[j] + b2[j]);
  }
  short* o = out + (size_t)row * kD + l * 12;
  *(short4v*)(o) = r0;
  *(short4v*)(o + 4) = r1;
  *(short4v*)(o + 8) = r2;
}

// ------------- tiled transpose: in[R][C] f32 -> out[C][R] bf16 -------------
__global__ __launch_bounds__(256) void transpose_bf16(const float* __restrict__ in,
                                                      short* __restrict__ out,
                                                      int R, int C) {
  __shared__ short tile[64][66];
  int c0 = blockIdx.x * 64, r0 = blockIdx.y * 64;
  int t = threadIdx.x;
  int c = t & 63, rr = t >> 6;
#pragma unroll
  for (int p = 0; p < 16; p++) {
    int r = p * 4 + rr;
    tile[r][c] = f2bf(in[(size_t)(r0 + r) * C + c0 + c]);
  }
  __syncthreads();
  int r2 = t & 63, cc = t >> 6;
#pragma unroll
  for (int p = 0; p < 16; p++) {
    int c2 = p * 4 + cc;
    out[(size_t)(c0 + c2) * R + r0 + r2] = tile[r2][c2];
  }
}

// pack Wq/Wk/Wv [H][64][64] -> wt[H][192][64] bf16 transposed
__global__ void pack_qkv(const float* __restrict__ Wq, const float* __restrict__ Wk,
                         const float* __restrict__ Wv, short* __restrict__ out) {
  int idx = blockIdx.x * 256 + threadIdx.x;
  if (idx >= kH * 192 * kd) return;
  int h = idx / (192 * kd);
  int j = (idx / kd) % 192;
  int k = idx % kd;
  int m = j >> 6, e = j & 63;
  const float* W = (m == 0) ? Wq : (m == 1) ? Wk : Wv;
  out[idx] = f2bf(W[((size_t)h * kd + k) * kd + e]);
}

// ---------------- QKV GEMM: per (64-token tile, head); 3 waves = q/k/v ----------------
__global__ __launch_bounds__(192) void qkv_gemm(const short* __restrict__ xn,
                                                const short* __restrict__ wt,
                                                const float* __restrict__ bq,
                                                const float* __restrict__ bk,
                                                const float* __restrict__ bv,
                                                short* __restrict__ Qb,
                                                short* __restrict__ Kb,
                                                short* __restrict__ Vb) {
  int t0 = blockIdx.x * 64;
  int h = blockIdx.y;
  __shared__ __align__(16) short As[64][72];
  __shared__ __align__(16) short Bs[192][72];
  int tid = threadIdx.x;
  for (int c = tid; c < 64 * 8; c += 192) {
    int row = c >> 3, c8 = c & 7;
    short8 v = {};
    int tok = t0 + row;
    if (tok < kTOK) v = *(const short8*)(xn + (size_t)tok * kD + h * kd + c8 * 8);
    *(short8*)&As[row][c8 * 8] = v;
  }
  const short* wth = wt + (size_t)h * 192 * kd;
  for (int c = tid; c < 192 * 8; c += 192) {
    int row = c >> 3, c8 = c & 7;
    *(short8*)&Bs[row][c8 * 8] = *(const short8*)(wth + row * kd + c8 * 8);
  }
  __syncthreads();
  int w = tid >> 6, l = tid & 63, l15 = l & 15, l4 = l >> 4;
  f32x4 acc[4][4] = {};
  short8 aF[4][2], bF[4][2];
#pragma unroll
  for (int rf = 0; rf < 4; rf++)
#pragma unroll
    for (int kk = 0; kk < 2; kk++)
      aF[rf][kk] = *(const short8*)&As[16 * rf + l15][32 * kk + 8 * l4];
#pragma unroll
  for (int cf = 0; cf < 4; cf++)
#pragma unroll
    for (int kk = 0; kk < 2; kk++)
      bF[cf][kk] = *(const short8*)&Bs[w * 64 + 16 * cf + l15][32 * kk + 8 * l4];
#pragma unroll
  for (int rf = 0; rf < 4; rf++)
#pragma unroll
    for (int cf = 0; cf < 4; cf++) {
      f32x4 c = acc[rf][cf];
      c = mfma16(aF[rf][0], bF[cf][0], c);
      c = mfma16(aF[rf][1], bF[cf][1], c);
      acc[rf][cf] = c;
    }
  const float* bias = (w == 0) ? bq : (w == 1) ? bk : bv;
  short* Out = (w == 0) ? Qb : (w == 1) ? Kb : Vb;
  float scale = (w == 0) ? 0.125f : 1.0f;
#pragma unroll
  for (int rf = 0; rf < 4; rf++) {
    int rowb = 16 * rf + 4 * l4;
#pragma unroll
    for (int cf = 0; cf < 4; cf++) {
      int col = 16 * cf + l15;
      float bs = bias[h * kd + col];
#pragma unroll
      for (int r = 0; r < 4; r++) {
        int tok = t0 + rowb + r;
        if (tok >= kTOK) continue;
        int bb = tok / kS, ssi = tok % kS;
        Out[(((size_t)bb * kH + h) * kS + ssi) * kd + col] =
            f2bf((acc[rf][cf][r] + bs) * scale);
      }
    }
  }
}

// -------- flash attention, swapped-QK^T 32x32 structure; fuses out = x + attn --------
__global__ __launch_bounds__(256) void attn_kernel(const short* __restrict__ Qb,
                                                   const short* __restrict__ Kb,
                                                   const short* __restrict__ Vb,
                                                   const float* __restrict__ x,
                                                   float* __restrict__ out) {
  int nwg = gridDim.x;                    // 1920
  int bid = blockIdx.x;
  int chunk = nwg >> 3;                   // 240
  int swz = (bid & 7) * chunk + (bid >> 3);
  int qt = swz % 5;
  int bh = swz / 5;
  int h = bh % kH;
  int b = bh / kH;
  const size_t baseHS = ((size_t)b * kH + h) * kS;
  __shared__ __align__(16) short Klds[2][64 * 64];
  __shared__ __align__(16) short Vlds[2][64 * 64];
  int tid = threadIdx.x;
  int w = tid >> 6, l = tid & 63;
  int l31 = l & 31, hi = l >> 5;
  int q0w = qt * 128 + w * 32;
  bool active = (q0w < kS);

  int qg = q0w + l31;
  const short* qp = Qb + (baseHS + (qg > 576 ? 576 : qg)) * kd + 8 * hi;
  short8 qf[4];
#pragma unroll
  for (int ks = 0; ks < 4; ks++) qf[ks] = *(const short8*)(qp + 16 * ks);

  auto stageK = [&](int kbase, short* dst) {
#pragma unroll
    for (int c = 0; c < 2; c++) {
      int chnk = tid + 256 * c;
      int row = chnk >> 3, sl = chnk & 7;
      int sr = kbase + row; if (sr > 576) sr = 576;
      load_lds16(Kb + (baseHS + sr) * kd + 8 * (sl ^ (row & 7)),
                 dst + (chnk & ~63) * 8);
    }
  };
  short4v vr0[2], vr1[2];
  auto stageV_load = [&](int kbase) {
#pragma unroll
    for (int c = 0; c < 2; c++) {
      int task = tid + 256 * c;
      int vp = task >> 4, vc = task & 15;
      int r0 = kbase + 2 * vp;     if (r0 > 576) r0 = 576;
      int r1 = kbase + 2 * vp + 1; if (r1 > 576) r1 = 576;
      vr0[c] = *(const short4v*)(Vb + (baseHS + r0) * kd + 4 * vc);
      vr1[c] = *(const short4v*)(Vb + (baseHS + r1) * kd + 4 * vc);
    }
  };
  auto stageV_write = [&](short* dst) {
#pragma unroll
    for (int c = 0; c < 2; c++) {
      int task = tid + 256 * c;
      int vp = task >> 4, vc = task & 15;
      int kv2 = 2 * vp;
#pragma unroll
      for (int j = 0; j < 4; j++) {
        int d = 4 * vc + j;
        *(unsigned*)((char*)dst + d * 128 + ((kv2 * 2) ^ ((d & 7) << 4))) =
            (unsigned)(unsigned short)vr0[c][j] |
            ((unsigned)(unsigned short)vr1[c][j] << 16);
      }
    }
  };

  stageK(0, Klds[0]);
  stageV_load(0);
  stageV_write(Vlds[0]);
  __syncthreads();

  f32x16 o0 = {}, o1 = {};
  float m_run = -1e30f, l_run = 0.f;
  int cur = 0;
  const int NT = 10;

  for (int kt = 0; kt < NT; kt++) {
    int kbase = kt * 64;
    bool has_next = (kt + 1 < NT);
    if (has_next) {
      stageK(kbase + 64, Klds[cur ^ 1]);
      stageV_load(kbase + 64);
    }
    u32x4 pa[4];
    if (active) {
      const char* Kc = (const char*)Klds[cur];
      f32x16 st0 = {}, st1 = {};
      __builtin_amdgcn_s_setprio(1);
#pragma unroll
      for (int ks = 0; ks < 4; ks++) {
        int xr = ((2 * ks + hi) ^ (l31 & 7)) << 4;
        short8 k0 = *(const short8*)(Kc + l31 * 128 + xr);
        short8 k1 = *(const short8*)(Kc + (32 + l31) * 128 + xr);
        st0 = mfma32(k0, qf[ks], st0);
        st1 = mfma32(k1, qf[ks], st1);
      }
      __builtin_amdgcn_s_setprio(0);
      if (kbase + 64 > kS) {
#pragma unroll
        for (int r = 0; r < 16; r++) {
          int cr = (r & 3) + 8 * (r >> 2) + 4 * hi;
          if (kbase + cr > 576)      st0[r] = -1e30f;
          if (kbase + 32 + cr > 576) st1[r] = -1e30f;
        }
      }
      float mx = st0[0];
#pragma unroll
      for (int r = 0; r < 16; r++) {
        mx = fmaxf(mx, st0[r]);
        mx = fmaxf(mx, st1[r]);
      }
      mx = fmaxf(mx, __shfl_xor(mx, 32, 64));
      bool need = !__all(mx <= m_run + 8.0f);
      if (need) {
        float mnew = fmaxf(m_run, mx);
        float al = __expf(m_run - mnew);
        m_run = mnew;
        l_run *= al;
#pragma unroll
        for (int r = 0; r < 16; r++) {
          int cr = (r & 3) + 8 * (r >> 2) + 4 * hi;
          float ar = __shfl(al, cr, 64);
          o0[r] *= ar;
          o1[r] *= ar;
        }
      }
      float rs = 0.f;
#pragma unroll
      for (int r = 0; r < 16; r++) {
        float p0 = __expf(st0[r] - m_run); st0[r] = p0;
        float p1 = __expf(st1[r] - m_run); st1[r] = p1;
        rs += p0 + p1;
      }
      rs += __shfl_xor(rs, 32, 64);
      l_run += rs;
      {
        unsigned a0 = cvtpk(st0[0], st0[1]),   b0 = cvtpk(st0[4], st0[5]);   pl32(a0, b0);
        unsigned a1 = cvtpk(st0[2], st0[3]),   b1 = cvtpk(st0[6], st0[7]);   pl32(a1, b1);
        pa[0] = (u32x4){a0, a1, b0, b1};
        unsigned c0 = cvtpk(st0[8], st0[9]),   d0 = cvtpk(st0[12], st0[13]); pl32(c0, d0);
        unsigned c1 = cvtpk(st0[10], st0[11]), d1 = cvtpk(st0[14], st0[15]); pl32(c1, d1);
        pa[1] = (u32x4){c0, c1, d0, d1};
        unsigned e0 = cvtpk(st1[0], st1[1]),   f0 = cvtpk(st1[4], st1[5]);   pl32(e0, f0);
        unsigned e1 = cvtpk(st1[2], st1[3]),   f1 = cvtpk(st1[6], st1[7]);   pl32(e1, f1);
        pa[2] = (u32x4){e0, e1, f0, f1};
        unsigned g0 = cvtpk(st1[8], st1[9]),   h0 = cvtpk(st1[12], st1[13]); pl32(g0, h0);
        unsigned g1 = cvtpk(st1[10], st1[11]), h1 = cvtpk(st1[14], st1[15]); pl32(g1, h1);
        pa[3] = (u32x4){g0, g1, h0, h1};
      }
      const char* Vc = (const char*)Vlds[cur];
      __builtin_amdgcn_s_setprio(1);
#pragma unroll
      for (int ks = 0; ks < 4; ks++) {
        int xr = ((2 * ks + hi) ^ (l31 & 7)) << 4;
        short8 v0 = *(const short8*)(Vc + l31 * 128 + xr);
        short8 v1 = *(const short8*)(Vc + (32 + l31) * 128 + xr);
        o0 = mfma32(__builtin_bit_cast(short8, pa[ks]), v0, o0);
        o1 = mfma32(__builtin_bit_cast(short8, pa[ks]), v1, o1);
      }
      __builtin_amdgcn_s_setprio(0);
    }
    if (has_next) stageV_write(Vlds[cur ^ 1]);
    __syncthreads();
    cur ^= 1;
  }

  if (active) {
#pragma unroll
    for (int r = 0; r < 16; r++) {
      int cr = (r & 3) + 8 * (r >> 2) + 4 * hi;
      int qq = q0w + cr;
      if (qq < kS) {
        float lq = __shfl(l_run, cr, 64);
        float rl = 1.0f / lq;
        size_t gi = ((size_t)b * kS + qq) * kD + h * kd + l31;
        out[gi]      = x[gi]      + o0[r] * rl;
        out[gi + 32] = x[gi + 32] + o1[r] * rl;
      } else {
        (void)__shfl(l_run, cr, 64);
      }
    }
  }
}

// ======== GEMM1: 256x256xBK64 single-buffer drain, 8 waves (4Mx2N,      ========
// ======== per-wave 64x128, acc[4][8]), 64KB LDS -> 2 blk/CU.            ========
// mode 0: tanh-GELU -> bf16 outb ; mode 1: outf += (residual accumulate, f32)
__global__ __launch_bounds__(512, 4) void gemm_big(const short* __restrict__ A,
                                                   const short* __restrict__ BT,
                                                   const float* __restrict__ bias,
                                                   short* __restrict__ outb,
                                                   float* __restrict__ outf,
                                                   int M, int N, int K, int mode) {
  __shared__ __align__(16) short As[256 * 64];  // 32 KiB
  __shared__ __align__(16) short Bs[256 * 64];  // 32 KiB

  int nwg = gridDim.x, bid = blockIdx.x;
  int q = nwg >> 3, r = nwg & 7;
  int xcd = bid & 7, lx = bid >> 3;
  int swz = (xcd < r ? xcd * (q + 1) : r * (q + 1) + (xcd - r) * q) + lx;
  int gn = N >> 8;
  int nt = swz % gn, mt = swz / gn;
  int m0 = mt << 8, n0 = nt << 8;

  int tid = threadIdx.x;
  int w = tid >> 6, l = tid & 63, l15 = l & 15, l4 = l >> 4;
  int wm = w >> 1, wn = w & 1;

  int srow = tid >> 3;                     // 0..63
  int sslot = (tid & 7) ^ (srow & 7);
  int sdst = (tid & ~63) * 8;              // wave-uniform dest (shorts)
  const short* Asrc = A + (size_t)(m0 + srow) * K + sslot * 8;
  const short* Bsrc = BT + (size_t)(n0 + srow) * K + sslot * 8;

  const char* ldsA = (const char*)As + wm * 8192;   // 64 rows each
  const char* ldsB = (const char*)Bs + wn * 16384;  // 128 rows each

  f32x4 acc[4][8] = {};

  for (int k0 = 0; k0 < K; k0 += 64) {
    __syncthreads();
#pragma unroll
    for (int i = 0; i < 4; i++)
      load_lds16(Asrc + (size_t)(64 * i) * K + k0, As + i * 4096 + sdst);
#pragma unroll
    for (int j = 0; j < 4; j++)
      load_lds16(Bsrc + (size_t)(64 * j) * K + k0, Bs + j * 4096 + sdst);
    __syncthreads();  // drain; sibling block covers the stall
#pragma unroll
    for (int kk = 0; kk < 2; kk++) {
      short8 aF[4], bF[8];
#pragma unroll
      for (int i = 0; i < 4; i++) {
        int ra = 16 * i + l15;
        aF[i] = *(const short8*)(ldsA + ra * 128 + (((kk * 4 + l4) ^ (ra & 7)) << 4));
      }
#pragma unroll
      for (int j = 0; j < 8; j++) {
        int rb = 16 * j + l15;
        bF[j] = *(const short8*)(ldsB + rb * 128 + (((kk * 4 + l4) ^ (rb & 7)) << 4));
      }
#pragma unroll
      for (int i = 0; i < 4; i++)
#pragma unroll
        for (int j = 0; j < 8; j++)
          acc[i][j] = mfma16(aF[i], bF[j], acc[i][j]);
    }
  }

#pragma unroll
  for (int i = 0; i < 4; i++) {
#pragma unroll
    for (int j = 0; j < 8; j++) {
      int col = n0 + wn * 128 + 16 * j + l15;
      float bs = bias[col];
#pragma unroll
      for (int rr = 0; rr < 4; rr++) {
        int row = m0 + wm * 64 + 16 * i + 4 * l4 + rr;
        if (row >= M) continue;
        float v = acc[i][j][rr] + bs;
        if (mode == 0) {
          outb[(size_t)row * N + col] = f2bf(gelu_f(v));
        } else {
          outf[(size_t)row * N + col] += v;
        }
      }
    }
  }
}

// ======== GEMM2: 128x128xBK64 drain loop, 32KB LDS, (256,4) — R10 winner ========
__global__ __launch_bounds__(256, 4) void gemm2b(const short* __restrict__ A,
                                                 const short* __restrict__ BT,
                                                 const float* __restrict__ bias,
                                                 float* __restrict__ outf,
                                                 int M, int N, int K) {
  __shared__ __align__(16) short As[128 * 64];  // 16 KiB
  __shared__ __align__(16) short Bs[128 * 64];  // 16 KiB

  int nwg = gridDim.x, bid = blockIdx.x;
  int q = nwg >> 3, r = nwg & 7;
  int xcd = bid & 7, lx = bid >> 3;
  int swz = (xcd < r ? xcd * (q + 1) : r * (q + 1) + (xcd - r) * q) + lx;
  int gn = N >> 7;  // 6
  int nt = swz % gn, mt = swz / gn;
  int m0 = mt << 7, n0 = nt << 7;

  int tid = threadIdx.x;
  int w = tid >> 6, l = tid & 63, l15 = l & 15, l4 = l >> 4;
  int wm = w >> 1, wn = w & 1;

  int srow = tid >> 3;                     // 0..31
  int sslot = (tid & 7) ^ (srow & 7);
  int sdst = (tid & ~63) * 8;              // wave-uniform dest (shorts)
  const short* Asrc = A + (size_t)(m0 + srow) * K + sslot * 8;
  const short* Bsrc = BT + (size_t)(n0 + srow) * K + sslot * 8;

  const char* ldsA = (const char*)As + wm * 8192;
  const char* ldsB = (const char*)Bs + wn * 8192;

  f32x4 acc[4][4] = {};

  for (int k0 = 0; k0 < K; k0 += 64) {
    __syncthreads();
#pragma unroll
    for (int i = 0; i < 4; i++)
      load_lds16(Asrc + (size_t)(32 * i) * K + k0, As + i * 2048 + sdst);
#pragma unroll
    for (int j = 0; j < 4; j++)
      load_lds16(Bsrc + (size_t)(32 * j) * K + k0, Bs + j * 2048 + sdst);
    __syncthreads();
#pragma unroll
    for (int kk = 0; kk < 2; kk++) {
      short8 aF[4], bF[4];
#pragma unroll
      for (int i = 0; i < 4; i++) {
        int ra = 16 * i + l15;
        aF[i] = *(const short8*)(ldsA + ra * 128 + (((kk * 4 + l4) ^ (ra & 7)) << 4));
        bF[i] = *(const short8*)(ldsB + ra * 128 + (((kk * 4 + l4) ^ (ra & 7)) << 4));
      }
#pragma unroll
      for (int i = 0; i < 4; i++)
#pragma unroll
        for (int j = 0; j < 4; j++)
          acc[i][j] = mfma16(aF[i], bF[j], acc[i][j]);
    }
  }

#pragma unroll
  for (int i = 0; i < 4; i++) {
#pragma unroll
    for (int j = 0; j < 4; j++) {
      int col = n0 + wn * 64 + 16 * j + l15;
      float bs = bias[col];
#pragma unroll
      for (int rr = 0; rr < 4; rr++) {
        int row = m0 + wm * 64 + 16 * i + 4 * l4 + rr;
        if (row >= M) continue;
        outf[(size_t)row * N + col] += acc[i][j][rr] + bs;
      }
    }
  }
}

extern "C" void kernel_launch(void* const* d_in, const int* in_sizes, int n_in,
                              void* d_out, int out_size, void* d_ws, size_t ws_size,
                              hipStream_t stream) {
  const float* x     = (const float*)d_in[0];
  const float* ln1_g = (const float*)d_in[1];
  const float* ln1_b = (const float*)d_in[2];
  const float* Wq    = (const float*)d_in[3];
  const float* bq    = (const float*)d_in[4];
  const float* Wk    = (const float*)d_in[5];
  const float* bk    = (const float*)d_in[6];
  const float* Wv    = (const float*)d_in[7];
  const float* bv    = (const float*)d_in[8];
  const float* ln2_g = (const float*)d_in[9];
  const float* ln2_b = (const float*)d_in[10];
  const float* W1    = (const float*)d_in[11];
  const float* b1    = (const float*)d_in[12];
  const float* W2    = (const float*)d_in[13];
  const float* b2    = (const float*)d_in[14];
  float* out = (float*)d_out;

  char* ws = (char*)d_ws;
  size_t off = 0;
  auto alloc = [&](size_t bytes) {
    size_t o = off;
    off += (bytes + 255) & ~(size_t)255;
    return o;
  };
  short* xn    = (short*)(ws + alloc((size_t)kTOK * kD * 2));
  short* wqkvT = (short*)(ws + alloc((size_t)kH * 192 * kd * 2));
  short* w1T   = (short*)(ws + alloc((size_t)kMLP * kD * 2));
  short* w2T   = (short*)(ws + alloc((size_t)kD * kMLP * 2));
  short* Qb    = (short*)(ws + alloc((size_t)kTOK * kD * 2));
  short* Kb    = (short*)(ws + alloc((size_t)kTOK * kD * 2));
  short* Vb    = (short*)(ws + alloc((size_t)kTOK * kD * 2));
  short* hbuf  = (short*)(ws + alloc((size_t)kMPAD * kD * 2));
  short* gbuf  = (short*)(ws + alloc((size_t)kMPAD * kMLP * 2));

  ln_kernel<<<kTOK / 4, 256, 0, stream>>>(x, ln1_g, ln1_b, xn);
  transpose_bf16<<<dim3(kMLP / 64, kD / 64), 256, 0, stream>>>(W1, w1T, kD, kMLP);
  transpose_bf16<<<dim3(kD / 64, kMLP / 64), 256, 0, stream>>>(W2, w2T, kMLP, kD);
  pack_qkv<<<(kH * 192 * kd + 255) / 256, 256, 0, stream>>>(Wq, Wk, Wv, wqkvT);
  qkv_gemm<<<dim3((kTOK + 63) / 64, kH), 192, 0, stream>>>(xn, wqkvT, bq, bk, bv, Qb, Kb, Vb);
  attn_kernel<<<5 * kH * kB, 256, 0, stream>>>(Qb, Kb, Vb, x, out);
  ln_kernel<<<kTOK / 4, 256, 0, stream>>>(out, ln2_g, ln2_b, hbuf);
  gemm_big<<<(kMPAD / 256) * (kMLP / 256), 512, 0, stream>>>(
      hbuf, w1T, b1, gbuf, nullptr, kTOK, kMLP, kD, 0);
  gemm2b<<<(kMPAD / 128) * (kD / 128), 256, 0, stream>>>(
      gbuf, w2T, b2, out, kTOK, kD, kMLP);
}

// Round 17
// 462.768 us; speedup vs baseline: 3.0738x; 3.0738x over previous
//
#include <hip/hip_runtime.h>
#include <hip/hip_bf16.h>

// ViT transformer block: B=32 S=577 D=768 H=12 d=64 MLP=3072, f32 in/out.
// R17: FINAL revert to measured-best configuration (R13/R14, 463.6us):
//      gemm_bb 256x128@(512,4), gemm2b 128x128@(256,4), swapped-QK^T attn
//      (XCD-chunk grid), wave-per-row LN. R16's 256x256 acc[4][8]=128 regs
//      spilled under the 128/wave budget (rule: acc <= 64 regs at 16 w/CU).

#define kB   32
#define kS   577
#define kD   768
#define kH   12
#define kd   64
#define kMLP 3072
#define kTOK (kB * kS)   // 18464
#define kMPAD 18688      // 73 * 256 = 146 * 128

typedef short short8 __attribute__((ext_vector_type(8)));
typedef short short4v __attribute__((ext_vector_type(4)));
typedef float f32x4 __attribute__((ext_vector_type(4)));
typedef float f32x16 __attribute__((ext_vector_type(16)));
typedef unsigned u32x4 __attribute__((ext_vector_type(4)));
typedef __bf16 bf16x8 __attribute__((ext_vector_type(8)));

__device__ inline short f2bf(float f) {
  unsigned u = __float_as_uint(f);
  unsigned r = (u + 0x7FFFu + ((u >> 16) & 1u)) >> 16;
  return (short)r;
}

__device__ inline f32x4 mfma16(short8 a, short8 b, f32x4 c) {
  return __builtin_amdgcn_mfma_f32_16x16x32_bf16(
      __builtin_bit_cast(bf16x8, a), __builtin_bit_cast(bf16x8, b), c, 0, 0, 0);
}

__device__ inline f32x16 mfma32(short8 a, short8 b, f32x16 c) {
  return __builtin_amdgcn_mfma_f32_32x32x16_bf16(
      __builtin_bit_cast(bf16x8, a), __builtin_bit_cast(bf16x8, b), c, 0, 0, 0);
}

__device__ inline void load_lds16(const short* g, short* l) {
  __builtin_amdgcn_global_load_lds(
      (__attribute__((address_space(1))) void*)(g),
      (__attribute__((address_space(3))) void*)(l), 16, 0, 0);
}

__device__ inline unsigned cvtpk(float lo, float hi) {
  unsigned r;
  asm("v_cvt_pk_bf16_f32 %0, %1, %2" : "=v"(r) : "v"(lo), "v"(hi));
  return r;
}

__device__ inline void pl32(unsigned &a, unsigned &b) {
  typedef int int2v __attribute__((ext_vector_type(2)));
  int2v r = __builtin_amdgcn_permlane32_swap((int)a, (int)b, false, false);
  a = (unsigned)r[0];
  b = (unsigned)r[1];
}

// NaN-safe tanh-GELU (max dev from exact erf-GELU ~4e-4)
__device__ inline float gelu_f(float x) {
  float u = x * x;
  float z = x * fmaf(0.0713548162f, u, 1.5957691216f);
  float e = __expf(z);
  return x - x / (e + 1.0f);
}

// ------- LayerNorm, wave-per-row: 4 rows/block, shuffle-only reduce -------
__global__ __launch_bounds__(256) void ln_kernel(const float* __restrict__ x,
                                                 const float* __restrict__ g,
                                                 const float* __restrict__ b,
                                                 short* __restrict__ out) {
  int row = blockIdx.x * 4 + (threadIdx.x >> 6);
  int l = threadIdx.x & 63;
  const float* xr = x + (size_t)row * kD + l * 12;
  f32x4 v0 = *(const f32x4*)(xr);
  f32x4 v1 = *(const f32x4*)(xr + 4);
  f32x4 v2 = *(const f32x4*)(xr + 8);
  float s = 0.f, ss = 0.f;
#pragma unroll
  for (int j = 0; j < 4; j++) {
    s += v0[j] + v1[j] + v2[j];
    ss += v0[j] * v0[j] + v1[j] * v1[j] + v2[j] * v2[j];
  }
#pragma unroll
  for (int off = 1; off < 64; off <<= 1) {
    s += __shfl_xor(s, off, 64);
    ss += __shfl_xor(ss, off, 64);
  }
  float mean = s * (1.f / kD);
  float var = ss * (1.f / kD) - mean * mean;
  float rstd = rsqrtf(var + 1e-5f);
  const float* gr = g + l * 12;
  const float* br = b + l * 12;
  f32x4 g0 = *(const f32x4*)(gr),     g1 = *(const f32x4*)(gr + 4),
        g2 = *(const f32x4*)(gr + 8);
  f32x4 b0 = *(const f32x4*)(br),     b1 = *(const f32x4*)(br + 4),
        b2 = *(const f32x4*)(br + 8);
  short4v r0, r1, r2;
#pragma unroll
  for (int j = 0; j < 4; j++) {
    r0[j] = f2bf((v0[j] - mean) * rstd * g0[j] + b0[j]);
    r1[j] = f2bf((v1[j] - mean) * rstd * g1[j] + b1[j]);
    r2[j] = f2bf((v2[j] - mean) * rstd * g2[j] + b2[j]);
  }
  short* o = out + (size_t)row * kD + l * 12;
  *(short4v*)(o) = r0;
  *(short4v*)(o + 4) = r1;
  *(short4v*)(o + 8) = r2;
}

// ------------- tiled transpose: in[R][C] f32 -> out[C][R] bf16 -------------
__global__ __launch_bounds__(256) void transpose_bf16(const float* __restrict__ in,
                                                      short* __restrict__ out,
                                                      int R, int C) {
  __shared__ short tile[64][66];
  int c0 = blockIdx.x * 64, r0 = blockIdx.y * 64;
  int t = threadIdx.x;
  int c = t & 63, rr = t >> 6;
#pragma unroll
  for (int p = 0; p < 16; p++) {
    int r = p * 4 + rr;
    tile[r][c] = f2bf(in[(size_t)(r0 + r) * C + c0 + c]);
  }
  __syncthreads();
  int r2 = t & 63, cc = t >> 6;
#pragma unroll
  for (int p = 0; p < 16; p++) {
    int c2 = p * 4 + cc;
    out[(size_t)(c0 + c2) * R + r0 + r2] = tile[r2][c2];
  }
}

// pack Wq/Wk/Wv [H][64][64] -> wt[H][192][64] bf16 transposed
__global__ void pack_qkv(const float* __restrict__ Wq, const float* __restrict__ Wk,
                         const float* __restrict__ Wv, short* __restrict__ out) {
  int idx = blockIdx.x * 256 + threadIdx.x;
  if (idx >= kH * 192 * kd) return;
  int h = idx / (192 * kd);
  int j = (idx / kd) % 192;
  int k = idx % kd;
  int m = j >> 6, e = j & 63;
  const float* W = (m == 0) ? Wq : (m == 1) ? Wk : Wv;
  out[idx] = f2bf(W[((size_t)h * kd + k) * kd + e]);
}

// ---------------- QKV GEMM: per (64-token tile, head); 3 waves = q/k/v ----------------
__global__ __launch_bounds__(192) void qkv_gemm(const short* __restrict__ xn,
                                                const short* __restrict__ wt,
                                                const float* __restrict__ bq,
                                                const float* __restrict__ bk,
                                                const float* __restrict__ bv,
                                                short* __restrict__ Qb,
                                                short* __restrict__ Kb,
                                                short* __restrict__ Vb) {
  int t0 = blockIdx.x * 64;
  int h = blockIdx.y;
  __shared__ __align__(16) short As[64][72];
  __shared__ __align__(16) short Bs[192][72];
  int tid = threadIdx.x;
  for (int c = tid; c < 64 * 8; c += 192) {
    int row = c >> 3, c8 = c & 7;
    short8 v = {};
    int tok = t0 + row;
    if (tok < kTOK) v = *(const short8*)(xn + (size_t)tok * kD + h * kd + c8 * 8);
    *(short8*)&As[row][c8 * 8] = v;
  }
  const short* wth = wt + (size_t)h * 192 * kd;
  for (int c = tid; c < 192 * 8; c += 192) {
    int row = c >> 3, c8 = c & 7;
    *(short8*)&Bs[row][c8 * 8] = *(const short8*)(wth + row * kd + c8 * 8);
  }
  __syncthreads();
  int w = tid >> 6, l = tid & 63, l15 = l & 15, l4 = l >> 4;
  f32x4 acc[4][4] = {};
  short8 aF[4][2], bF[4][2];
#pragma unroll
  for (int rf = 0; rf < 4; rf++)
#pragma unroll
    for (int kk = 0; kk < 2; kk++)
      aF[rf][kk] = *(const short8*)&As[16 * rf + l15][32 * kk + 8 * l4];
#pragma unroll
  for (int cf = 0; cf < 4; cf++)
#pragma unroll
    for (int kk = 0; kk < 2; kk++)
      bF[cf][kk] = *(const short8*)&Bs[w * 64 + 16 * cf + l15][32 * kk + 8 * l4];
#pragma unroll
  for (int rf = 0; rf < 4; rf++)
#pragma unroll
    for (int cf = 0; cf < 4; cf++) {
      f32x4 c = acc[rf][cf];
      c = mfma16(aF[rf][0], bF[cf][0], c);
      c = mfma16(aF[rf][1], bF[cf][1], c);
      acc[rf][cf] = c;
    }
  const float* bias = (w == 0) ? bq : (w == 1) ? bk : bv;
  short* Out = (w == 0) ? Qb : (w == 1) ? Kb : Vb;
  float scale = (w == 0) ? 0.125f : 1.0f;
#pragma unroll
  for (int rf = 0; rf < 4; rf++) {
    int rowb = 16 * rf + 4 * l4;
#pragma unroll
    for (int cf = 0; cf < 4; cf++) {
      int col = 16 * cf + l15;
      float bs = bias[h * kd + col];
#pragma unroll
      for (int r = 0; r < 4; r++) {
        int tok = t0 + rowb + r;
        if (tok >= kTOK) continue;
        int bb = tok / kS, ssi = tok % kS;
        Out[(((size_t)bb * kH + h) * kS + ssi) * kd + col] =
            f2bf((acc[rf][cf][r] + bs) * scale);
      }
    }
  }
}

// -------- flash attention, swapped-QK^T 32x32 structure; fuses out = x + attn --------
__global__ __launch_bounds__(256) void attn_kernel(const short* __restrict__ Qb,
                                                   const short* __restrict__ Kb,
                                                   const short* __restrict__ Vb,
                                                   const float* __restrict__ x,
                                                   float* __restrict__ out) {
  int nwg = gridDim.x;                    // 1920
  int bid = blockIdx.x;
  int chunk = nwg >> 3;                   // 240
  int swz = (bid & 7) * chunk + (bid >> 3);
  int qt = swz % 5;
  int bh = swz / 5;
  int h = bh % kH;
  int b = bh / kH;
  const size_t baseHS = ((size_t)b * kH + h) * kS;
  __shared__ __align__(16) short Klds[2][64 * 64];
  __shared__ __align__(16) short Vlds[2][64 * 64];
  int tid = threadIdx.x;
  int w = tid >> 6, l = tid & 63;
  int l31 = l & 31, hi = l >> 5;
  int q0w = qt * 128 + w * 32;
  bool active = (q0w < kS);

  int qg = q0w + l31;
  const short* qp = Qb + (baseHS + (qg > 576 ? 576 : qg)) * kd + 8 * hi;
  short8 qf[4];
#pragma unroll
  for (int ks = 0; ks < 4; ks++) qf[ks] = *(const short8*)(qp + 16 * ks);

  auto stageK = [&](int kbase, short* dst) {
#pragma unroll
    for (int c = 0; c < 2; c++) {
      int chnk = tid + 256 * c;
      int row = chnk >> 3, sl = chnk & 7;
      int sr = kbase + row; if (sr > 576) sr = 576;
      load_lds16(Kb + (baseHS + sr) * kd + 8 * (sl ^ (row & 7)),
                 dst + (chnk & ~63) * 8);
    }
  };
  short4v vr0[2], vr1[2];
  auto stageV_load = [&](int kbase) {
#pragma unroll
    for (int c = 0; c < 2; c++) {
      int task = tid + 256 * c;
      int vp = task >> 4, vc = task & 15;
      int r0 = kbase + 2 * vp;     if (r0 > 576) r0 = 576;
      int r1 = kbase + 2 * vp + 1; if (r1 > 576) r1 = 576;
      vr0[c] = *(const short4v*)(Vb + (baseHS + r0) * kd + 4 * vc);
      vr1[c] = *(const short4v*)(Vb + (baseHS + r1) * kd + 4 * vc);
    }
  };
  auto stageV_write = [&](short* dst) {
#pragma unroll
    for (int c = 0; c < 2; c++) {
      int task = tid + 256 * c;
      int vp = task >> 4, vc = task & 15;
      int kv2 = 2 * vp;
#pragma unroll
      for (int j = 0; j < 4; j++) {
        int d = 4 * vc + j;
        *(unsigned*)((char*)dst + d * 128 + ((kv2 * 2) ^ ((d & 7) << 4))) =
            (unsigned)(unsigned short)vr0[c][j] |
            ((unsigned)(unsigned short)vr1[c][j] << 16);
      }
    }
  };

  stageK(0, Klds[0]);
  stageV_load(0);
  stageV_write(Vlds[0]);
  __syncthreads();

  f32x16 o0 = {}, o1 = {};
  float m_run = -1e30f, l_run = 0.f;
  int cur = 0;
  const int NT = 10;

  for (int kt = 0; kt < NT; kt++) {
    int kbase = kt * 64;
    bool has_next = (kt + 1 < NT);
    if (has_next) {
      stageK(kbase + 64, Klds[cur ^ 1]);
      stageV_load(kbase + 64);
    }
    u32x4 pa[4];
    if (active) {
      const char* Kc = (const char*)Klds[cur];
      f32x16 st0 = {}, st1 = {};
      __builtin_amdgcn_s_setprio(1);
#pragma unroll
      for (int ks = 0; ks < 4; ks++) {
        int xr = ((2 * ks + hi) ^ (l31 & 7)) << 4;
        short8 k0 = *(const short8*)(Kc + l31 * 128 + xr);
        short8 k1 = *(const short8*)(Kc + (32 + l31) * 128 + xr);
        st0 = mfma32(k0, qf[ks], st0);
        st1 = mfma32(k1, qf[ks], st1);
      }
      __builtin_amdgcn_s_setprio(0);
      if (kbase + 64 > kS) {
#pragma unroll
        for (int r = 0; r < 16; r++) {
          int cr = (r & 3) + 8 * (r >> 2) + 4 * hi;
          if (kbase + cr > 576)      st0[r] = -1e30f;
          if (kbase + 32 + cr > 576) st1[r] = -1e30f;
        }
      }
      float mx = st0[0];
#pragma unroll
      for (int r = 0; r < 16; r++) {
        mx = fmaxf(mx, st0[r]);
        mx = fmaxf(mx, st1[r]);
      }
      mx = fmaxf(mx, __shfl_xor(mx, 32, 64));
      bool need = !__all(mx <= m_run + 8.0f);
      if (need) {
        float mnew = fmaxf(m_run, mx);
        float al = __expf(m_run - mnew);
        m_run = mnew;
        l_run *= al;
#pragma unroll
        for (int r = 0; r < 16; r++) {
          int cr = (r & 3) + 8 * (r >> 2) + 4 * hi;
          float ar = __shfl(al, cr, 64);
          o0[r] *= ar;
          o1[r] *= ar;
        }
      }
      float rs = 0.f;
#pragma unroll
      for (int r = 0; r < 16; r++) {
        float p0 = __expf(st0[r] - m_run); st0[r] = p0;
        float p1 = __expf(st1[r] - m_run); st1[r] = p1;
        rs += p0 + p1;
      }
      rs += __shfl_xor(rs, 32, 64);
      l_run += rs;
      {
        unsigned a0 = cvtpk(st0[0], st0[1]),   b0 = cvtpk(st0[4], st0[5]);   pl32(a0, b0);
        unsigned a1 = cvtpk(st0[2], st0[3]),   b1 = cvtpk(st0[6], st0[7]);   pl32(a1, b1);
        pa[0] = (u32x4){a0, a1, b0, b1};
        unsigned c0 = cvtpk(st0[8], st0[9]),   d0 = cvtpk(st0[12], st0[13]); pl32(c0, d0);
        unsigned c1 = cvtpk(st0[10], st0[11]), d1 = cvtpk(st0[14], st0[15]); pl32(c1, d1);
        pa[1] = (u32x4){c0, c1, d0, d1};
        unsigned e0 = cvtpk(st1[0], st1[1]),   f0 = cvtpk(st1[4], st1[5]);   pl32(e0, f0);
        unsigned e1 = cvtpk(st1[2], st1[3]),   f1 = cvtpk(st1[6], st1[7]);   pl32(e1, f1);
        pa[2] = (u32x4){e0, e1, f0, f1};
        unsigned g0 = cvtpk(st1[8], st1[9]),   h0 = cvtpk(st1[12], st1[13]); pl32(g0, h0);
        unsigned g1 = cvtpk(st1[10], st1[11]), h1 = cvtpk(st1[14], st1[15]); pl32(g1, h1);
        pa[3] = (u32x4){g0, g1, h0, h1};
      }
      const char* Vc = (const char*)Vlds[cur];
      __builtin_amdgcn_s_setprio(1);
#pragma unroll
      for (int ks = 0; ks < 4; ks++) {
        int xr = ((2 * ks + hi) ^ (l31 & 7)) << 4;
        short8 v0 = *(const short8*)(Vc + l31 * 128 + xr);
        short8 v1 = *(const short8*)(Vc + (32 + l31) * 128 + xr);
        o0 = mfma32(__builtin_bit_cast(short8, pa[ks]), v0, o0);
        o1 = mfma32(__builtin_bit_cast(short8, pa[ks]), v1, o1);
      }
      __builtin_amdgcn_s_setprio(0);
    }
    if (has_next) stageV_write(Vlds[cur ^ 1]);
    __syncthreads();
    cur ^= 1;
  }

  if (active) {
#pragma unroll
    for (int r = 0; r < 16; r++) {
      int cr = (r & 3) + 8 * (r >> 2) + 4 * hi;
      int qq = q0w + cr;
      if (qq < kS) {
        float lq = __shfl(l_run, cr, 64);
        float rl = 1.0f / lq;
        size_t gi = ((size_t)b * kS + qq) * kD + h * kd + l31;
        out[gi]      = x[gi]      + o0[r] * rl;
        out[gi + 32] = x[gi + 32] + o1[r] * rl;
      } else {
        (void)__shfl(l_run, cr, 64);
      }
    }
  }
}

// ======== GEMM1: 256x128xBK64, single-buffer 48KB LDS, 8 waves (4Mx2N), ========
// ======== launch_bounds(512,4) — winner config (~143us).                ========
__global__ __launch_bounds__(512, 4) void gemm_bb(const short* __restrict__ A,
                                                  const short* __restrict__ BT,
                                                  const float* __restrict__ bias,
                                                  short* __restrict__ outb,
                                                  float* __restrict__ outf,
                                                  int M, int N, int K, int mode) {
  __shared__ __align__(16) short As[256 * 64];  // 32 KiB
  __shared__ __align__(16) short Bs[128 * 64];  // 16 KiB

  int nwg = gridDim.x, bid = blockIdx.x;
  int q = nwg >> 3, r = nwg & 7;
  int xcd = bid & 7, lx = bid >> 3;
  int swz = (xcd < r ? xcd * (q + 1) : r * (q + 1) + (xcd - r) * q) + lx;
  int gn = N >> 7;
  int nt = swz % gn, mt = swz / gn;
  int m0 = mt << 8, n0 = nt << 7;

  int tid = threadIdx.x;
  int w = tid >> 6, l = tid & 63, l15 = l & 15, l4 = l >> 4;
  int wm = w >> 1, wn = w & 1;

  int srow = tid >> 3;
  int sslot = (tid & 7) ^ (srow & 7);
  int sdst = (tid & ~63) * 8;
  const short* Asrc = A + (size_t)(m0 + srow) * K + sslot * 8;
  const short* Bsrc = BT + (size_t)(n0 + srow) * K + sslot * 8;

  const char* ldsA = (const char*)As + wm * 8192;
  const char* ldsB = (const char*)Bs + wn * 8192;

  f32x4 acc[4][4] = {};

  for (int k0 = 0; k0 < K; k0 += 64) {
    __syncthreads();
#pragma unroll
    for (int i = 0; i < 4; i++)
      load_lds16(Asrc + (size_t)(64 * i) * K + k0, As + i * 4096 + sdst);
#pragma unroll
    for (int j = 0; j < 2; j++)
      load_lds16(Bsrc + (size_t)(64 * j) * K + k0, Bs + j * 4096 + sdst);
    __syncthreads();
#pragma unroll
    for (int kk = 0; kk < 2; kk++) {
      short8 aF[4], bF[4];
#pragma unroll
      for (int i = 0; i < 4; i++) {
        int ra = 16 * i + l15;
        aF[i] = *(const short8*)(ldsA + ra * 128 + (((kk * 4 + l4) ^ (ra & 7)) << 4));
        bF[i] = *(const short8*)(ldsB + ra * 128 + (((kk * 4 + l4) ^ (ra & 7)) << 4));
      }
#pragma unroll
      for (int i = 0; i < 4; i++)
#pragma unroll
        for (int j = 0; j < 4; j++)
          acc[i][j] = mfma16(aF[i], bF[j], acc[i][j]);
    }
  }

#pragma unroll
  for (int i = 0; i < 4; i++) {
#pragma unroll
    for (int j = 0; j < 4; j++) {
      int col = n0 + wn * 64 + 16 * j + l15;
      float bs = bias[col];
#pragma unroll
      for (int rr = 0; rr < 4; rr++) {
        int row = m0 + wm * 64 + 16 * i + 4 * l4 + rr;
        if (row >= M) continue;
        float v = acc[i][j][rr] + bs;
        if (mode == 0) {
          outb[(size_t)row * N + col] = f2bf(gelu_f(v));
        } else {
          outf[(size_t)row * N + col] += v;
        }
      }
    }
  }
}

// ======== GEMM2: 128x128xBK64 drain loop, 32KB LDS, (256,4) — R10 winner ========
__global__ __launch_bounds__(256, 4) void gemm2b(const short* __restrict__ A,
                                                 const short* __restrict__ BT,
                                                 const float* __restrict__ bias,
                                                 float* __restrict__ outf,
                                                 int M, int N, int K) {
  __shared__ __align__(16) short As[128 * 64];  // 16 KiB
  __shared__ __align__(16) short Bs[128 * 64];  // 16 KiB

  int nwg = gridDim.x, bid = blockIdx.x;
  int q = nwg >> 3, r = nwg & 7;
  int xcd = bid & 7, lx = bid >> 3;
  int swz = (xcd < r ? xcd * (q + 1) : r * (q + 1) + (xcd - r) * q) + lx;
  int gn = N >> 7;  // 6
  int nt = swz % gn, mt = swz / gn;
  int m0 = mt << 7, n0 = nt << 7;

  int tid = threadIdx.x;
  int w = tid >> 6, l = tid & 63, l15 = l & 15, l4 = l >> 4;
  int wm = w >> 1, wn = w & 1;

  int srow = tid >> 3;                     // 0..31
  int sslot = (tid & 7) ^ (srow & 7);
  int sdst = (tid & ~63) * 8;              // wave-uniform dest (shorts)
  const short* Asrc = A + (size_t)(m0 + srow) * K + sslot * 8;
  const short* Bsrc = BT + (size_t)(n0 + srow) * K + sslot * 8;

  const char* ldsA = (const char*)As + wm * 8192;
  const char* ldsB = (const char*)Bs + wn * 8192;

  f32x4 acc[4][4] = {};

  for (int k0 = 0; k0 < K; k0 += 64) {
    __syncthreads();
#pragma unroll
    for (int i = 0; i < 4; i++)
      load_lds16(Asrc + (size_t)(32 * i) * K + k0, As + i * 2048 + sdst);
#pragma unroll
    for (int j = 0; j < 4; j++)
      load_lds16(Bsrc + (size_t)(32 * j) * K + k0, Bs + j * 2048 + sdst);
    __syncthreads();
#pragma unroll
    for (int kk = 0; kk < 2; kk++) {
      short8 aF[4], bF[4];
#pragma unroll
      for (int i = 0; i < 4; i++) {
        int ra = 16 * i + l15;
        aF[i] = *(const short8*)(ldsA + ra * 128 + (((kk * 4 + l4) ^ (ra & 7)) << 4));
        bF[i] = *(const short8*)(ldsB + ra * 128 + (((kk * 4 + l4) ^ (ra & 7)) << 4));
      }
#pragma unroll
      for (int i = 0; i < 4; i++)
#pragma unroll
        for (int j = 0; j < 4; j++)
          acc[i][j] = mfma16(aF[i], bF[j], acc[i][j]);
    }
  }

#pragma unroll
  for (int i = 0; i < 4; i++) {
#pragma unroll
    for (int j = 0; j < 4; j++) {
      int col = n0 + wn * 64 + 16 * j + l15;
      float bs = bias[col];
#pragma unroll
      for (int rr = 0; rr < 4; rr++) {
        int row = m0 + wm * 64 + 16 * i + 4 * l4 + rr;
        if (row >= M) continue;
        outf[(size_t)row * N + col] += acc[i][j][rr] + bs;
      }
    }
  }
}

extern "C" void kernel_launch(void* const* d_in, const int* in_sizes, int n_in,
                              void* d_out, int out_size, void* d_ws, size_t ws_size,
                              hipStream_t stream) {
  const float* x     = (const float*)d_in[0];
  const float* ln1_g = (const float*)d_in[1];
  const float* ln1_b = (const float*)d_in[2];
  const float* Wq    = (const float*)d_in[3];
  const float* bq    = (const float*)d_in[4];
  const float* Wk    = (const float*)d_in[5];
  const float* bk    = (const float*)d_in[6];
  const float* Wv    = (const float*)d_in[7];
  const float* bv    = (const float*)d_in[8];
  const float* ln2_g = (const float*)d_in[9];
  const float* ln2_b = (const float*)d_in[10];
  const float* W1    = (const float*)d_in[11];
  const float* b1    = (const float*)d_in[12];
  const float* W2    = (const float*)d_in[13];
  const float* b2    = (const float*)d_in[14];
  float* out = (float*)d_out;

  char* ws = (char*)d_ws;
  size_t off = 0;
  auto alloc = [&](size_t bytes) {
    size_t o = off;
    off += (bytes + 255) & ~(size_t)255;
    return o;
  };
  short* xn    = (short*)(ws + alloc((size_t)kTOK * kD * 2));
  short* wqkvT = (short*)(ws + alloc((size_t)kH * 192 * kd * 2));
  short* w1T   = (short*)(ws + alloc((size_t)kMLP * kD * 2));
  short* w2T   = (short*)(ws + alloc((size_t)kD * kMLP * 2));
  short* Qb    = (short*)(ws + alloc((size_t)kTOK * kD * 2));
  short* Kb    = (short*)(ws + alloc((size_t)kTOK * kD * 2));
  short* Vb    = (short*)(ws + alloc((size_t)kTOK * kD * 2));
  short* hbuf  = (short*)(ws + alloc((size_t)kMPAD * kD * 2));
  short* gbuf  = (short*)(ws + alloc((size_t)kMPAD * kMLP * 2));

  ln_kernel<<<kTOK / 4, 256, 0, stream>>>(x, ln1_g, ln1_b, xn);
  transpose_bf16<<<dim3(kMLP / 64, kD / 64), 256, 0, stream>>>(W1, w1T, kD, kMLP);
  transpose_bf16<<<dim3(kD / 64, kMLP / 64), 256, 0, stream>>>(W2, w2T, kMLP, kD);
  pack_qkv<<<(kH * 192 * kd + 255) / 256, 256, 0, stream>>>(Wq, Wk, Wv, wqkvT);
  qkv_gemm<<<dim3((kTOK + 63) / 64, kH), 192, 0, stream>>>(xn, wqkvT, bq, bk, bv, Qb, Kb, Vb);
  attn_kernel<<<5 * kH * kB, 256, 0, stream>>>(Qb, Kb, Vb, x, out);
  ln_kernel<<<kTOK / 4, 256, 0, stream>>>(out, ln2_g, ln2_b, hbuf);
  gemm_bb<<<(kMPAD / 256) * (kMLP / 128), 512, 0, stream>>>(
      hbuf, w1T, b1, gbuf, nullptr, kTOK, kMLP, kD, 0);
  gemm2b<<<(kMPAD / 128) * (kD / 128), 256, 0, stream>>>(
      gbuf, w2T, b2, out, kTOK, kD, kMLP);
}

// Round 18
// 453.218 us; speedup vs baseline: 3.1386x; 1.0211x over previous
//
#include <hip/hip_runtime.h>
#include <hip/hip_bf16.h>

// ViT transformer block: B=32 S=577 D=768 H=12 d=64 MLP=3072, f32 in/out.
// R18: non-GEMM tail cleanup: (1) transposes+pack merged into one prep_w
//      kernel (2 fewer launch gaps); (2) qkv_gemm -> 128-token tiles, 384
//      threads (6 waves = 2 halves x QKV), half the blocks/B-staging.
//      GEMMs/attention/LN byte-identical to R17 winner (462.8us).

#define kB   32
#define kS   577
#define kD   768
#define kH   12
#define kd   64
#define kMLP 3072
#define kTOK (kB * kS)   // 18464
#define kMPAD 18688      // 73 * 256 = 146 * 128

typedef short short8 __attribute__((ext_vector_type(8)));
typedef short short4v __attribute__((ext_vector_type(4)));
typedef float f32x4 __attribute__((ext_vector_type(4)));
typedef float f32x16 __attribute__((ext_vector_type(16)));
typedef unsigned u32x4 __attribute__((ext_vector_type(4)));
typedef __bf16 bf16x8 __attribute__((ext_vector_type(8)));

__device__ inline short f2bf(float f) {
  unsigned u = __float_as_uint(f);
  unsigned r = (u + 0x7FFFu + ((u >> 16) & 1u)) >> 16;
  return (short)r;
}

__device__ inline f32x4 mfma16(short8 a, short8 b, f32x4 c) {
  return __builtin_amdgcn_mfma_f32_16x16x32_bf16(
      __builtin_bit_cast(bf16x8, a), __builtin_bit_cast(bf16x8, b), c, 0, 0, 0);
}

__device__ inline f32x16 mfma32(short8 a, short8 b, f32x16 c) {
  return __builtin_amdgcn_mfma_f32_32x32x16_bf16(
      __builtin_bit_cast(bf16x8, a), __builtin_bit_cast(bf16x8, b), c, 0, 0, 0);
}

__device__ inline void load_lds16(const short* g, short* l) {
  __builtin_amdgcn_global_load_lds(
      (__attribute__((address_space(1))) void*)(g),
      (__attribute__((address_space(3))) void*)(l), 16, 0, 0);
}

__device__ inline unsigned cvtpk(float lo, float hi) {
  unsigned r;
  asm("v_cvt_pk_bf16_f32 %0, %1, %2" : "=v"(r) : "v"(lo), "v"(hi));
  return r;
}

__device__ inline void pl32(unsigned &a, unsigned &b) {
  typedef int int2v __attribute__((ext_vector_type(2)));
  int2v r = __builtin_amdgcn_permlane32_swap((int)a, (int)b, false, false);
  a = (unsigned)r[0];
  b = (unsigned)r[1];
}

// NaN-safe tanh-GELU (max dev from exact erf-GELU ~4e-4)
__device__ inline float gelu_f(float x) {
  float u = x * x;
  float z = x * fmaf(0.0713548162f, u, 1.5957691216f);
  float e = __expf(z);
  return x - x / (e + 1.0f);
}

// ------- LayerNorm, wave-per-row: 4 rows/block, shuffle-only reduce -------
__global__ __launch_bounds__(256) void ln_kernel(const float* __restrict__ x,
                                                 const float* __restrict__ g,
                                                 const float* __restrict__ b,
                                                 short* __restrict__ out) {
  int row = blockIdx.x * 4 + (threadIdx.x >> 6);
  int l = threadIdx.x & 63;
  const float* xr = x + (size_t)row * kD + l * 12;
  f32x4 v0 = *(const f32x4*)(xr);
  f32x4 v1 = *(const f32x4*)(xr + 4);
  f32x4 v2 = *(const f32x4*)(xr + 8);
  float s = 0.f, ss = 0.f;
#pragma unroll
  for (int j = 0; j < 4; j++) {
    s += v0[j] + v1[j] + v2[j];
    ss += v0[j] * v0[j] + v1[j] * v1[j] + v2[j] * v2[j];
  }
#pragma unroll
  for (int off = 1; off < 64; off <<= 1) {
    s += __shfl_xor(s, off, 64);
    ss += __shfl_xor(ss, off, 64);
  }
  float mean = s * (1.f / kD);
  float var = ss * (1.f / kD) - mean * mean;
  float rstd = rsqrtf(var + 1e-5f);
  const float* gr = g + l * 12;
  const float* br = b + l * 12;
  f32x4 g0 = *(const f32x4*)(gr),     g1 = *(const f32x4*)(gr + 4),
        g2 = *(const f32x4*)(gr + 8);
  f32x4 b0 = *(const f32x4*)(br),     b1 = *(const f32x4*)(br + 4),
        b2 = *(const f32x4*)(br + 8);
  short4v r0, r1, r2;
#pragma unroll
  for (int j = 0; j < 4; j++) {
    r0[j] = f2bf((v0[j] - mean) * rstd * g0[j] + b0[j]);
    r1[j] = f2bf((v1[j] - mean) * rstd * g1[j] + b1[j]);
    r2[j] = f2bf((v2[j] - mean) * rstd * g2[j] + b2[j]);
  }
  short* o = out + (size_t)row * kD + l * 12;
  *(short4v*)(o) = r0;
  *(short4v*)(o + 4) = r1;
  *(short4v*)(o + 8) = r2;
}

// ---- fused weight prep: W1^T, W2^T (tiled transpose) + QKV pack, 1 kernel ----
__device__ inline void tr_tile(const float* __restrict__ in, short* __restrict__ out,
                               int R, int C, int c0, int r0) {
  __shared__ short tile[64][66];
  int t = threadIdx.x;
  int c = t & 63, rr = t >> 6;
#pragma unroll
  for (int p = 0; p < 16; p++) {
    int r = p * 4 + rr;
    tile[r][c] = f2bf(in[(size_t)(r0 + r) * C + c0 + c]);
  }
  __syncthreads();
  int r2 = t & 63, cc = t >> 6;
#pragma unroll
  for (int p = 0; p < 16; p++) {
    int c2 = p * 4 + cc;
    out[(size_t)(c0 + c2) * R + r0 + r2] = tile[r2][c2];
  }
}

__global__ __launch_bounds__(256) void prep_w(const float* __restrict__ W1,
                                              const float* __restrict__ W2,
                                              const float* __restrict__ Wq,
                                              const float* __restrict__ Wk,
                                              const float* __restrict__ Wv,
                                              short* __restrict__ w1T,
                                              short* __restrict__ w2T,
                                              short* __restrict__ wqkvT) {
  int bid = blockIdx.x;
  if (bid < 576) {                       // W1 [kD][kMLP] -> w1T [kMLP][kD]
    int bx = bid % (kMLP / 64), by = bid / (kMLP / 64);
    tr_tile(W1, w1T, kD, kMLP, bx * 64, by * 64);
  } else if (bid < 1152) {               // W2 [kMLP][kD] -> w2T [kD][kMLP]
    int b2 = bid - 576;
    int bx = b2 % (kD / 64), by = b2 / (kD / 64);
    tr_tile(W2, w2T, kMLP, kD, bx * 64, by * 64);
  } else {                               // pack Wq/Wk/Wv -> wqkvT[h][192][64]
    int idx = (bid - 1152) * 256 + threadIdx.x;   // < 576*256 == kH*192*kd
    int h = idx / (192 * kd);
    int j = (idx / kd) % 192;
    int k = idx % kd;
    int m = j >> 6, e = j & 63;
    const float* W = (m == 0) ? Wq : (m == 1) ? Wk : Wv;
    wqkvT[idx] = f2bf(W[((size_t)h * kd + k) * kd + e]);
  }
}

// ---- QKV GEMM: 128-token tile x head; 6 waves = 2 token-halves x {Q,K,V} ----
// Q output pre-scaled by 1/8 (= 1/sqrt(64)).
__global__ __launch_bounds__(384) void qkv_gemm(const short* __restrict__ xn,
                                                const short* __restrict__ wt,
                                                const float* __restrict__ bq,
                                                const float* __restrict__ bk,
                                                const float* __restrict__ bv,
                                                short* __restrict__ Qb,
                                                short* __restrict__ Kb,
                                                short* __restrict__ Vb) {
  int t0 = blockIdx.x * 128;
  int h = blockIdx.y;
  __shared__ __align__(16) short As[128][72];
  __shared__ __align__(16) short Bs[192][72];
  int tid = threadIdx.x;
  for (int c = tid; c < 128 * 8; c += 384) {
    int row = c >> 3, c8 = c & 7;
    short8 v = {};
    int tok = t0 + row;
    if (tok < kTOK) v = *(const short8*)(xn + (size_t)tok * kD + h * kd + c8 * 8);
    *(short8*)&As[row][c8 * 8] = v;
  }
  const short* wth = wt + (size_t)h * 192 * kd;
  for (int c = tid; c < 192 * 8; c += 384) {
    int row = c >> 3, c8 = c & 7;
    *(short8*)&Bs[row][c8 * 8] = *(const short8*)(wth + row * kd + c8 * 8);
  }
  __syncthreads();
  int w = tid >> 6, l = tid & 63, l15 = l & 15, l4 = l >> 4;
  int m = w % 3;            // 0=Q 1=K 2=V
  int half = w / 3;         // token half (0/1)
  f32x4 acc[4][4] = {};
  short8 aF[4][2], bF[4][2];
#pragma unroll
  for (int rf = 0; rf < 4; rf++)
#pragma unroll
    for (int kk = 0; kk < 2; kk++)
      aF[rf][kk] = *(const short8*)&As[half * 64 + 16 * rf + l15][32 * kk + 8 * l4];
#pragma unroll
  for (int cf = 0; cf < 4; cf++)
#pragma unroll
    for (int kk = 0; kk < 2; kk++)
      bF[cf][kk] = *(const short8*)&Bs[m * 64 + 16 * cf + l15][32 * kk + 8 * l4];
#pragma unroll
  for (int rf = 0; rf < 4; rf++)
#pragma unroll
    for (int cf = 0; cf < 4; cf++) {
      f32x4 c = acc[rf][cf];
      c = mfma16(aF[rf][0], bF[cf][0], c);
      c = mfma16(aF[rf][1], bF[cf][1], c);
      acc[rf][cf] = c;
    }
  const float* bias = (m == 0) ? bq : (m == 1) ? bk : bv;
  short* Out = (m == 0) ? Qb : (m == 1) ? Kb : Vb;
  float scale = (m == 0) ? 0.125f : 1.0f;
#pragma unroll
  for (int rf = 0; rf < 4; rf++) {
    int rowb = half * 64 + 16 * rf + 4 * l4;
#pragma unroll
    for (int cf = 0; cf < 4; cf++) {
      int col = 16 * cf + l15;
      float bs = bias[h * kd + col];
#pragma unroll
      for (int r = 0; r < 4; r++) {
        int tok = t0 + rowb + r;
        if (tok >= kTOK) continue;
        int bb = tok / kS, ssi = tok % kS;
        Out[(((size_t)bb * kH + h) * kS + ssi) * kd + col] =
            f2bf((acc[rf][cf][r] + bs) * scale);
      }
    }
  }
}

// -------- flash attention, swapped-QK^T 32x32 structure; fuses out = x + attn --------
__global__ __launch_bounds__(256) void attn_kernel(const short* __restrict__ Qb,
                                                   const short* __restrict__ Kb,
                                                   const short* __restrict__ Vb,
                                                   const float* __restrict__ x,
                                                   float* __restrict__ out) {
  int nwg = gridDim.x;                    // 1920
  int bid = blockIdx.x;
  int chunk = nwg >> 3;                   // 240
  int swz = (bid & 7) * chunk + (bid >> 3);
  int qt = swz % 5;
  int bh = swz / 5;
  int h = bh % kH;
  int b = bh / kH;
  const size_t baseHS = ((size_t)b * kH + h) * kS;
  __shared__ __align__(16) short Klds[2][64 * 64];
  __shared__ __align__(16) short Vlds[2][64 * 64];
  int tid = threadIdx.x;
  int w = tid >> 6, l = tid & 63;
  int l31 = l & 31, hi = l >> 5;
  int q0w = qt * 128 + w * 32;
  bool active = (q0w < kS);

  int qg = q0w + l31;
  const short* qp = Qb + (baseHS + (qg > 576 ? 576 : qg)) * kd + 8 * hi;
  short8 qf[4];
#pragma unroll
  for (int ks = 0; ks < 4; ks++) qf[ks] = *(const short8*)(qp + 16 * ks);

  auto stageK = [&](int kbase, short* dst) {
#pragma unroll
    for (int c = 0; c < 2; c++) {
      int chnk = tid + 256 * c;
      int row = chnk >> 3, sl = chnk & 7;
      int sr = kbase + row; if (sr > 576) sr = 576;
      load_lds16(Kb + (baseHS + sr) * kd + 8 * (sl ^ (row & 7)),
                 dst + (chnk & ~63) * 8);
    }
  };
  short4v vr0[2], vr1[2];
  auto stageV_load = [&](int kbase) {
#pragma unroll
    for (int c = 0; c < 2; c++) {
      int task = tid + 256 * c;
      int vp = task >> 4, vc = task & 15;
      int r0 = kbase + 2 * vp;     if (r0 > 576) r0 = 576;
      int r1 = kbase + 2 * vp + 1; if (r1 > 576) r1 = 576;
      vr0[c] = *(const short4v*)(Vb + (baseHS + r0) * kd + 4 * vc);
      vr1[c] = *(const short4v*)(Vb + (baseHS + r1) * kd + 4 * vc);
    }
  };
  auto stageV_write = [&](short* dst) {
#pragma unroll
    for (int c = 0; c < 2; c++) {
      int task = tid + 256 * c;
      int vp = task >> 4, vc = task & 15;
      int kv2 = 2 * vp;
#pragma unroll
      for (int j = 0; j < 4; j++) {
        int d = 4 * vc + j;
        *(unsigned*)((char*)dst + d * 128 + ((kv2 * 2) ^ ((d & 7) << 4))) =
            (unsigned)(unsigned short)vr0[c][j] |
            ((unsigned)(unsigned short)vr1[c][j] << 16);
      }
    }
  };

  stageK(0, Klds[0]);
  stageV_load(0);
  stageV_write(Vlds[0]);
  __syncthreads();

  f32x16 o0 = {}, o1 = {};
  float m_run = -1e30f, l_run = 0.f;
  int cur = 0;
  const int NT = 10;

  for (int kt = 0; kt < NT; kt++) {
    int kbase = kt * 64;
    bool has_next = (kt + 1 < NT);
    if (has_next) {
      stageK(kbase + 64, Klds[cur ^ 1]);
      stageV_load(kbase + 64);
    }
    u32x4 pa[4];
    if (active) {
      const char* Kc = (const char*)Klds[cur];
      f32x16 st0 = {}, st1 = {};
      __builtin_amdgcn_s_setprio(1);
#pragma unroll
      for (int ks = 0; ks < 4; ks++) {
        int xr = ((2 * ks + hi) ^ (l31 & 7)) << 4;
        short8 k0 = *(const short8*)(Kc + l31 * 128 + xr);
        short8 k1 = *(const short8*)(Kc + (32 + l31) * 128 + xr);
        st0 = mfma32(k0, qf[ks], st0);
        st1 = mfma32(k1, qf[ks], st1);
      }
      __builtin_amdgcn_s_setprio(0);
      if (kbase + 64 > kS) {
#pragma unroll
        for (int r = 0; r < 16; r++) {
          int cr = (r & 3) + 8 * (r >> 2) + 4 * hi;
          if (kbase + cr > 576)      st0[r] = -1e30f;
          if (kbase + 32 + cr > 576) st1[r] = -1e30f;
        }
      }
      float mx = st0[0];
#pragma unroll
      for (int r = 0; r < 16; r++) {
        mx = fmaxf(mx, st0[r]);
        mx = fmaxf(mx, st1[r]);
      }
      mx = fmaxf(mx, __shfl_xor(mx, 32, 64));
      bool need = !__all(mx <= m_run + 8.0f);
      if (need) {
        float mnew = fmaxf(m_run, mx);
        float al = __expf(m_run - mnew);
        m_run = mnew;
        l_run *= al;
#pragma unroll
        for (int r = 0; r < 16; r++) {
          int cr = (r & 3) + 8 * (r >> 2) + 4 * hi;
          float ar = __shfl(al, cr, 64);
          o0[r] *= ar;
          o1[r] *= ar;
        }
      }
      float rs = 0.f;
#pragma unroll
      for (int r = 0; r < 16; r++) {
        float p0 = __expf(st0[r] - m_run); st0[r] = p0;
        float p1 = __expf(st1[r] - m_run); st1[r] = p1;
        rs += p0 + p1;
      }
      rs += __shfl_xor(rs, 32, 64);
      l_run += rs;
      {
        unsigned a0 = cvtpk(st0[0], st0[1]),   b0 = cvtpk(st0[4], st0[5]);   pl32(a0, b0);
        unsigned a1 = cvtpk(st0[2], st0[3]),   b1 = cvtpk(st0[6], st0[7]);   pl32(a1, b1);
        pa[0] = (u32x4){a0, a1, b0, b1};
        unsigned c0 = cvtpk(st0[8], st0[9]),   d0 = cvtpk(st0[12], st0[13]); pl32(c0, d0);
        unsigned c1 = cvtpk(st0[10], st0[11]), d1 = cvtpk(st0[14], st0[15]); pl32(c1, d1);
        pa[1] = (u32x4){c0, c1, d0, d1};
        unsigned e0 = cvtpk(st1[0], st1[1]),   f0 = cvtpk(st1[4], st1[5]);   pl32(e0, f0);
        unsigned e1 = cvtpk(st1[2], st1[3]),   f1 = cvtpk(st1[6], st1[7]);   pl32(e1, f1);
        pa[2] = (u32x4){e0, e1, f0, f1};
        unsigned g0 = cvtpk(st1[8], st1[9]),   h0 = cvtpk(st1[12], st1[13]); pl32(g0, h0);
        unsigned g1 = cvtpk(st1[10], st1[11]), h1 = cvtpk(st1[14], st1[15]); pl32(g1, h1);
        pa[3] = (u32x4){g0, g1, h0, h1};
      }
      const char* Vc = (const char*)Vlds[cur];
      __builtin_amdgcn_s_setprio(1);
#pragma unroll
      for (int ks = 0; ks < 4; ks++) {
        int xr = ((2 * ks + hi) ^ (l31 & 7)) << 4;
        short8 v0 = *(const short8*)(Vc + l31 * 128 + xr);
        short8 v1 = *(const short8*)(Vc + (32 + l31) * 128 + xr);
        o0 = mfma32(__builtin_bit_cast(short8, pa[ks]), v0, o0);
        o1 = mfma32(__builtin_bit_cast(short8, pa[ks]), v1, o1);
      }
      __builtin_amdgcn_s_setprio(0);
    }
    if (has_next) stageV_write(Vlds[cur ^ 1]);
    __syncthreads();
    cur ^= 1;
  }

  if (active) {
#pragma unroll
    for (int r = 0; r < 16; r++) {
      int cr = (r & 3) + 8 * (r >> 2) + 4 * hi;
      int qq = q0w + cr;
      if (qq < kS) {
        float lq = __shfl(l_run, cr, 64);
        float rl = 1.0f / lq;
        size_t gi = ((size_t)b * kS + qq) * kD + h * kd + l31;
        out[gi]      = x[gi]      + o0[r] * rl;
        out[gi + 32] = x[gi + 32] + o1[r] * rl;
      } else {
        (void)__shfl(l_run, cr, 64);
      }
    }
  }
}

// ======== GEMM1: 256x128xBK64, single-buffer 48KB LDS, 8 waves (4Mx2N), ========
// ======== launch_bounds(512,4) — winner config (~143us).                ========
__global__ __launch_bounds__(512, 4) void gemm_bb(const short* __restrict__ A,
                                                  const short* __restrict__ BT,
                                                  const float* __restrict__ bias,
                                                  short* __restrict__ outb,
                                                  float* __restrict__ outf,
                                                  int M, int N, int K, int mode) {
  __shared__ __align__(16) short As[256 * 64];  // 32 KiB
  __shared__ __align__(16) short Bs[128 * 64];  // 16 KiB

  int nwg = gridDim.x, bid = blockIdx.x;
  int q = nwg >> 3, r = nwg & 7;
  int xcd = bid & 7, lx = bid >> 3;
  int swz = (xcd < r ? xcd * (q + 1) : r * (q + 1) + (xcd - r) * q) + lx;
  int gn = N >> 7;
  int nt = swz % gn, mt = swz / gn;
  int m0 = mt << 8, n0 = nt << 7;

  int tid = threadIdx.x;
  int w = tid >> 6, l = tid & 63, l15 = l & 15, l4 = l >> 4;
  int wm = w >> 1, wn = w & 1;

  int srow = tid >> 3;
  int sslot = (tid & 7) ^ (srow & 7);
  int sdst = (tid & ~63) * 8;
  const short* Asrc = A + (size_t)(m0 + srow) * K + sslot * 8;
  const short* Bsrc = BT + (size_t)(n0 + srow) * K + sslot * 8;

  const char* ldsA = (const char*)As + wm * 8192;
  const char* ldsB = (const char*)Bs + wn * 8192;

  f32x4 acc[4][4] = {};

  for (int k0 = 0; k0 < K; k0 += 64) {
    __syncthreads();
#pragma unroll
    for (int i = 0; i < 4; i++)
      load_lds16(Asrc + (size_t)(64 * i) * K + k0, As + i * 4096 + sdst);
#pragma unroll
    for (int j = 0; j < 2; j++)
      load_lds16(Bsrc + (size_t)(64 * j) * K + k0, Bs + j * 4096 + sdst);
    __syncthreads();
#pragma unroll
    for (int kk = 0; kk < 2; kk++) {
      short8 aF[4], bF[4];
#pragma unroll
      for (int i = 0; i < 4; i++) {
        int ra = 16 * i + l15;
        aF[i] = *(const short8*)(ldsA + ra * 128 + (((kk * 4 + l4) ^ (ra & 7)) << 4));
        bF[i] = *(const short8*)(ldsB + ra * 128 + (((kk * 4 + l4) ^ (ra & 7)) << 4));
      }
#pragma unroll
      for (int i = 0; i < 4; i++)
#pragma unroll
        for (int j = 0; j < 4; j++)
          acc[i][j] = mfma16(aF[i], bF[j], acc[i][j]);
    }
  }

#pragma unroll
  for (int i = 0; i < 4; i++) {
#pragma unroll
    for (int j = 0; j < 4; j++) {
      int col = n0 + wn * 64 + 16 * j + l15;
      float bs = bias[col];
#pragma unroll
      for (int rr = 0; rr < 4; rr++) {
        int row = m0 + wm * 64 + 16 * i + 4 * l4 + rr;
        if (row >= M) continue;
        float v = acc[i][j][rr] + bs;
        if (mode == 0) {
          outb[(size_t)row * N + col] = f2bf(gelu_f(v));
        } else {
          outf[(size_t)row * N + col] += v;
        }
      }
    }
  }
}

// ======== GEMM2: 128x128xBK64 drain loop, 32KB LDS, (256,4) — R10 winner ========
__global__ __launch_bounds__(256, 4) void gemm2b(const short* __restrict__ A,
                                                 const short* __restrict__ BT,
                                                 const float* __restrict__ bias,
                                                 float* __restrict__ outf,
                                                 int M, int N, int K) {
  __shared__ __align__(16) short As[128 * 64];  // 16 KiB
  __shared__ __align__(16) short Bs[128 * 64];  // 16 KiB

  int nwg = gridDim.x, bid = blockIdx.x;
  int q = nwg >> 3, r = nwg & 7;
  int xcd = bid & 7, lx = bid >> 3;
  int swz = (xcd < r ? xcd * (q + 1) : r * (q + 1) + (xcd - r) * q) + lx;
  int gn = N >> 7;  // 6
  int nt = swz % gn, mt = swz / gn;
  int m0 = mt << 7, n0 = nt << 7;

  int tid = threadIdx.x;
  int w = tid >> 6, l = tid & 63, l15 = l & 15, l4 = l >> 4;
  int wm = w >> 1, wn = w & 1;

  int srow = tid >> 3;                     // 0..31
  int sslot = (tid & 7) ^ (srow & 7);
  int sdst = (tid & ~63) * 8;              // wave-uniform dest (shorts)
  const short* Asrc = A + (size_t)(m0 + srow) * K + sslot * 8;
  const short* Bsrc = BT + (size_t)(n0 + srow) * K + sslot * 8;

  const char* ldsA = (const char*)As + wm * 8192;
  const char* ldsB = (const char*)Bs + wn * 8192;

  f32x4 acc[4][4] = {};

  for (int k0 = 0; k0 < K; k0 += 64) {
    __syncthreads();
#pragma unroll
    for (int i = 0; i < 4; i++)
      load_lds16(Asrc + (size_t)(32 * i) * K + k0, As + i * 2048 + sdst);
#pragma unroll
    for (int j = 0; j < 4; j++)
      load_lds16(Bsrc + (size_t)(32 * j) * K + k0, Bs + j * 2048 + sdst);
    __syncthreads();
#pragma unroll
    for (int kk = 0; kk < 2; kk++) {
      short8 aF[4], bF[4];
#pragma unroll
      for (int i = 0; i < 4; i++) {
        int ra = 16 * i + l15;
        aF[i] = *(const short8*)(ldsA + ra * 128 + (((kk * 4 + l4) ^ (ra & 7)) << 4));
        bF[i] = *(const short8*)(ldsB + ra * 128 + (((kk * 4 + l4) ^ (ra & 7)) << 4));
      }
#pragma unroll
      for (int i = 0; i < 4; i++)
#pragma unroll
        for (int j = 0; j < 4; j++)
          acc[i][j] = mfma16(aF[i], bF[j], acc[i][j]);
    }
  }

#pragma unroll
  for (int i = 0; i < 4; i++) {
#pragma unroll
    for (int j = 0; j < 4; j++) {
      int col = n0 + wn * 64 + 16 * j + l15;
      float bs = bias[col];
#pragma unroll
      for (int rr = 0; rr < 4; rr++) {
        int row = m0 + wm * 64 + 16 * i + 4 * l4 + rr;
        if (row >= M) continue;
        outf[(size_t)row * N + col] += acc[i][j][rr] + bs;
      }
    }
  }
}

extern "C" void kernel_launch(void* const* d_in, const int* in_sizes, int n_in,
                              void* d_out, int out_size, void* d_ws, size_t ws_size,
                              hipStream_t stream) {
  const float* x     = (const float*)d_in[0];
  const float* ln1_g = (const float*)d_in[1];
  const float* ln1_b = (const float*)d_in[2];
  const float* Wq    = (const float*)d_in[3];
  const float* bq    = (const float*)d_in[4];
  const float* Wk    = (const float*)d_in[5];
  const float* bk    = (const float*)d_in[6];
  const float* Wv    = (const float*)d_in[7];
  const float* bv    = (const float*)d_in[8];
  const float* ln2_g = (const float*)d_in[9];
  const float* ln2_b = (const float*)d_in[10];
  const float* W1    = (const float*)d_in[11];
  const float* b1    = (const float*)d_in[12];
  const float* W2    = (const float*)d_in[13];
  const float* b2    = (const float*)d_in[14];
  float* out = (float*)d_out;

  char* ws = (char*)d_ws;
  size_t off = 0;
  auto alloc = [&](size_t bytes) {
    size_t o = off;
    off += (bytes + 255) & ~(size_t)255;
    return o;
  };
  short* xn    = (short*)(ws + alloc((size_t)kTOK * kD * 2));
  short* wqkvT = (short*)(ws + alloc((size_t)kH * 192 * kd * 2));
  short* w1T   = (short*)(ws + alloc((size_t)kMLP * kD * 2));
  short* w2T   = (short*)(ws + alloc((size_t)kD * kMLP * 2));
  short* Qb    = (short*)(ws + alloc((size_t)kTOK * kD * 2));
  short* Kb    = (short*)(ws + alloc((size_t)kTOK * kD * 2));
  short* Vb    = (short*)(ws + alloc((size_t)kTOK * kD * 2));
  short* hbuf  = (short*)(ws + alloc((size_t)kMPAD * kD * 2));
  short* gbuf  = (short*)(ws + alloc((size_t)kMPAD * kMLP * 2));

  ln_kernel<<<kTOK / 4, 256, 0, stream>>>(x, ln1_g, ln1_b, xn);
  prep_w<<<1728, 256, 0, stream>>>(W1, W2, Wq, Wk, Wv, w1T, w2T, wqkvT);
  qkv_gemm<<<dim3((kTOK + 127) / 128, kH), 384, 0, stream>>>(
      xn, wqkvT, bq, bk, bv, Qb, Kb, Vb);
  attn_kernel<<<5 * kH * kB, 256, 0, stream>>>(Qb, Kb, Vb, x, out);
  ln_kernel<<<kTOK / 4, 256, 0, stream>>>(out, ln2_g, ln2_b, hbuf);
  gemm_bb<<<(kMPAD / 256) * (kMLP / 128), 512, 0, stream>>>(
      hbuf, w1T, b1, gbuf, nullptr, kTOK, kMLP, kD, 0);
  gemm2b<<<(kMPAD / 128) * (kD / 128), 256, 0, stream>>>(
      gbuf, w2T, b2, out, kTOK, kD, kMLP);
}

// Round 19
// 450.001 us; speedup vs baseline: 3.1610x; 1.0071x over previous
//
#include <hip/hip_runtime.h>
#include <hip/hip_bf16.h>

// ViT transformer block: B=32 S=577 D=768 H=12 d=64 MLP=3072, f32 in/out.
// R19: merge LN1 + weight prep (W1^T, W2^T, QKV pack) into one range-
//      partitioned kernel (one fewer launch gap; LN BW overlaps prep).
//      Everything else byte-identical to R18 (453.2us).

#define kB   32
#define kS   577
#define kD   768
#define kH   12
#define kd   64
#define kMLP 3072
#define kTOK (kB * kS)   // 18464
#define kMPAD 18688      // 73 * 256 = 146 * 128

typedef short short8 __attribute__((ext_vector_type(8)));
typedef short short4v __attribute__((ext_vector_type(4)));
typedef float f32x4 __attribute__((ext_vector_type(4)));
typedef float f32x16 __attribute__((ext_vector_type(16)));
typedef unsigned u32x4 __attribute__((ext_vector_type(4)));
typedef __bf16 bf16x8 __attribute__((ext_vector_type(8)));

__device__ inline short f2bf(float f) {
  unsigned u = __float_as_uint(f);
  unsigned r = (u + 0x7FFFu + ((u >> 16) & 1u)) >> 16;
  return (short)r;
}

__device__ inline f32x4 mfma16(short8 a, short8 b, f32x4 c) {
  return __builtin_amdgcn_mfma_f32_16x16x32_bf16(
      __builtin_bit_cast(bf16x8, a), __builtin_bit_cast(bf16x8, b), c, 0, 0, 0);
}

__device__ inline f32x16 mfma32(short8 a, short8 b, f32x16 c) {
  return __builtin_amdgcn_mfma_f32_32x32x16_bf16(
      __builtin_bit_cast(bf16x8, a), __builtin_bit_cast(bf16x8, b), c, 0, 0, 0);
}

__device__ inline void load_lds16(const short* g, short* l) {
  __builtin_amdgcn_global_load_lds(
      (__attribute__((address_space(1))) void*)(g),
      (__attribute__((address_space(3))) void*)(l), 16, 0, 0);
}

__device__ inline unsigned cvtpk(float lo, float hi) {
  unsigned r;
  asm("v_cvt_pk_bf16_f32 %0, %1, %2" : "=v"(r) : "v"(lo), "v"(hi));
  return r;
}

__device__ inline void pl32(unsigned &a, unsigned &b) {
  typedef int int2v __attribute__((ext_vector_type(2)));
  int2v r = __builtin_amdgcn_permlane32_swap((int)a, (int)b, false, false);
  a = (unsigned)r[0];
  b = (unsigned)r[1];
}

// NaN-safe tanh-GELU (max dev from exact erf-GELU ~4e-4)
__device__ inline float gelu_f(float x) {
  float u = x * x;
  float z = x * fmaf(0.0713548162f, u, 1.5957691216f);
  float e = __expf(z);
  return x - x / (e + 1.0f);
}

// ---- LN body: one wave normalizes one row (l = lane) ----
__device__ inline void ln_row(const float* __restrict__ x,
                              const float* __restrict__ g,
                              const float* __restrict__ b,
                              short* __restrict__ out, int row, int l) {
  const float* xr = x + (size_t)row * kD + l * 12;
  f32x4 v0 = *(const f32x4*)(xr);
  f32x4 v1 = *(const f32x4*)(xr + 4);
  f32x4 v2 = *(const f32x4*)(xr + 8);
  float s = 0.f, ss = 0.f;
#pragma unroll
  for (int j = 0; j < 4; j++) {
    s += v0[j] + v1[j] + v2[j];
    ss += v0[j] * v0[j] + v1[j] * v1[j] + v2[j] * v2[j];
  }
#pragma unroll
  for (int off = 1; off < 64; off <<= 1) {
    s += __shfl_xor(s, off, 64);
    ss += __shfl_xor(ss, off, 64);
  }
  float mean = s * (1.f / kD);
  float var = ss * (1.f / kD) - mean * mean;
  float rstd = rsqrtf(var + 1e-5f);
  const float* gr = g + l * 12;
  const float* br = b + l * 12;
  f32x4 g0 = *(const f32x4*)(gr), g1 = *(const f32x4*)(gr + 4),
        g2 = *(const f32x4*)(gr + 8);
  f32x4 b0 = *(const f32x4*)(br), b1 = *(const f32x4*)(br + 4),
        b2 = *(const f32x4*)(br + 8);
  short4v r0, r1, r2;
#pragma unroll
  for (int j = 0; j < 4; j++) {
    r0[j] = f2bf((v0[j] - mean) * rstd * g0[j] + b0[j]);
    r1[j] = f2bf((v1[j] - mean) * rstd * g1[j] + b1[j]);
    r2[j] = f2bf((v2[j] - mean) * rstd * g2[j] + b2[j]);
  }
  short* o = out + (size_t)row * kD + l * 12;
  *(short4v*)(o) = r0;
  *(short4v*)(o + 4) = r1;
  *(short4v*)(o + 8) = r2;
}

// ------- LayerNorm (standalone, for LN2): 4 rows/block -------
__global__ __launch_bounds__(256) void ln_kernel(const float* __restrict__ x,
                                                 const float* __restrict__ g,
                                                 const float* __restrict__ b,
                                                 short* __restrict__ out) {
  ln_row(x, g, b, out, blockIdx.x * 4 + (threadIdx.x >> 6), threadIdx.x & 63);
}

// ---- 64x64 transpose tile helper (f32 in -> bf16 out, transposed) ----
__device__ inline void tr_tile(const float* __restrict__ in, short* __restrict__ out,
                               int R, int C, int c0, int r0) {
  __shared__ short tile[64][66];
  int t = threadIdx.x;
  int c = t & 63, rr = t >> 6;
#pragma unroll
  for (int p = 0; p < 16; p++) {
    int r = p * 4 + rr;
    tile[r][c] = f2bf(in[(size_t)(r0 + r) * C + c0 + c]);
  }
  __syncthreads();
  int r2 = t & 63, cc = t >> 6;
#pragma unroll
  for (int p = 0; p < 16; p++) {
    int c2 = p * 4 + cc;
    out[(size_t)(c0 + c2) * R + r0 + r2] = tile[r2][c2];
  }
}

// ---- fused LN1 + weight prep: blocks [0,4616) LN rows; then W1/W2/QKV ----
__global__ __launch_bounds__(256) void ln_prep(const float* __restrict__ x,
                                               const float* __restrict__ ln1_g,
                                               const float* __restrict__ ln1_b,
                                               short* __restrict__ xn,
                                               const float* __restrict__ W1,
                                               const float* __restrict__ W2,
                                               const float* __restrict__ Wq,
                                               const float* __restrict__ Wk,
                                               const float* __restrict__ Wv,
                                               short* __restrict__ w1T,
                                               short* __restrict__ w2T,
                                               short* __restrict__ wqkvT) {
  int bid = blockIdx.x;
  if (bid < kTOK / 4) {                  // LN1: 4 rows per block
    ln_row(x, ln1_g, ln1_b, xn, bid * 4 + (threadIdx.x >> 6), threadIdx.x & 63);
    return;
  }
  bid -= kTOK / 4;
  if (bid < 576) {                       // W1 [kD][kMLP] -> w1T [kMLP][kD]
    int bx = bid % (kMLP / 64), by = bid / (kMLP / 64);
    tr_tile(W1, w1T, kD, kMLP, bx * 64, by * 64);
  } else if (bid < 1152) {               // W2 [kMLP][kD] -> w2T [kD][kMLP]
    int b2 = bid - 576;
    int bx = b2 % (kD / 64), by = b2 / (kD / 64);
    tr_tile(W2, w2T, kMLP, kD, bx * 64, by * 64);
  } else {                               // pack Wq/Wk/Wv -> wqkvT[h][192][64]
    int idx = (bid - 1152) * 256 + threadIdx.x;   // < 576*256 == kH*192*kd
    int h = idx / (192 * kd);
    int j = (idx / kd) % 192;
    int k = idx % kd;
    int m = j >> 6, e = j & 63;
    const float* W = (m == 0) ? Wq : (m == 1) ? Wk : Wv;
    wqkvT[idx] = f2bf(W[((size_t)h * kd + k) * kd + e]);
  }
}

// ---- QKV GEMM: 128-token tile x head; 6 waves = 2 token-halves x {Q,K,V} ----
// Q output pre-scaled by 1/8 (= 1/sqrt(64)).
__global__ __launch_bounds__(384) void qkv_gemm(const short* __restrict__ xn,
                                                const short* __restrict__ wt,
                                                const float* __restrict__ bq,
                                                const float* __restrict__ bk,
                                                const float* __restrict__ bv,
                                                short* __restrict__ Qb,
                                                short* __restrict__ Kb,
                                                short* __restrict__ Vb) {
  int t0 = blockIdx.x * 128;
  int h = blockIdx.y;
  __shared__ __align__(16) short As[128][72];
  __shared__ __align__(16) short Bs[192][72];
  int tid = threadIdx.x;
  for (int c = tid; c < 128 * 8; c += 384) {
    int row = c >> 3, c8 = c & 7;
    short8 v = {};
    int tok = t0 + row;
    if (tok < kTOK) v = *(const short8*)(xn + (size_t)tok * kD + h * kd + c8 * 8);
    *(short8*)&As[row][c8 * 8] = v;
  }
  const short* wth = wt + (size_t)h * 192 * kd;
  for (int c = tid; c < 192 * 8; c += 384) {
    int row = c >> 3, c8 = c & 7;
    *(short8*)&Bs[row][c8 * 8] = *(const short8*)(wth + row * kd + c8 * 8);
  }
  __syncthreads();
  int w = tid >> 6, l = tid & 63, l15 = l & 15, l4 = l >> 4;
  int m = w % 3;            // 0=Q 1=K 2=V
  int half = w / 3;         // token half (0/1)
  f32x4 acc[4][4] = {};
  short8 aF[4][2], bF[4][2];
#pragma unroll
  for (int rf = 0; rf < 4; rf++)
#pragma unroll
    for (int kk = 0; kk < 2; kk++)
      aF[rf][kk] = *(const short8*)&As[half * 64 + 16 * rf + l15][32 * kk + 8 * l4];
#pragma unroll
  for (int cf = 0; cf < 4; cf++)
#pragma unroll
    for (int kk = 0; kk < 2; kk++)
      bF[cf][kk] = *(const short8*)&Bs[m * 64 + 16 * cf + l15][32 * kk + 8 * l4];
#pragma unroll
  for (int rf = 0; rf < 4; rf++)
#pragma unroll
    for (int cf = 0; cf < 4; cf++) {
      f32x4 c = acc[rf][cf];
      c = mfma16(aF[rf][0], bF[cf][0], c);
      c = mfma16(aF[rf][1], bF[cf][1], c);
      acc[rf][cf] = c;
    }
  const float* bias = (m == 0) ? bq : (m == 1) ? bk : bv;
  short* Out = (m == 0) ? Qb : (m == 1) ? Kb : Vb;
  float scale = (m == 0) ? 0.125f : 1.0f;
#pragma unroll
  for (int rf = 0; rf < 4; rf++) {
    int rowb = half * 64 + 16 * rf + 4 * l4;
#pragma unroll
    for (int cf = 0; cf < 4; cf++) {
      int col = 16 * cf + l15;
      float bs = bias[h * kd + col];
#pragma unroll
      for (int r = 0; r < 4; r++) {
        int tok = t0 + rowb + r;
        if (tok >= kTOK) continue;
        int bb = tok / kS, ssi = tok % kS;
        Out[(((size_t)bb * kH + h) * kS + ssi) * kd + col] =
            f2bf((acc[rf][cf][r] + bs) * scale);
      }
    }
  }
}

// -------- flash attention, swapped-QK^T 32x32 structure; fuses out = x + attn --------
__global__ __launch_bounds__(256) void attn_kernel(const short* __restrict__ Qb,
                                                   const short* __restrict__ Kb,
                                                   const short* __restrict__ Vb,
                                                   const float* __restrict__ x,
                                                   float* __restrict__ out) {
  int nwg = gridDim.x;                    // 1920
  int bid = blockIdx.x;
  int chunk = nwg >> 3;                   // 240
  int swz = (bid & 7) * chunk + (bid >> 3);
  int qt = swz % 5;
  int bh = swz / 5;
  int h = bh % kH;
  int b = bh / kH;
  const size_t baseHS = ((size_t)b * kH + h) * kS;
  __shared__ __align__(16) short Klds[2][64 * 64];
  __shared__ __align__(16) short Vlds[2][64 * 64];
  int tid = threadIdx.x;
  int w = tid >> 6, l = tid & 63;
  int l31 = l & 31, hi = l >> 5;
  int q0w = qt * 128 + w * 32;
  bool active = (q0w < kS);

  int qg = q0w + l31;
  const short* qp = Qb + (baseHS + (qg > 576 ? 576 : qg)) * kd + 8 * hi;
  short8 qf[4];
#pragma unroll
  for (int ks = 0; ks < 4; ks++) qf[ks] = *(const short8*)(qp + 16 * ks);

  auto stageK = [&](int kbase, short* dst) {
#pragma unroll
    for (int c = 0; c < 2; c++) {
      int chnk = tid + 256 * c;
      int row = chnk >> 3, sl = chnk & 7;
      int sr = kbase + row; if (sr > 576) sr = 576;
      load_lds16(Kb + (baseHS + sr) * kd + 8 * (sl ^ (row & 7)),
                 dst + (chnk & ~63) * 8);
    }
  };
  short4v vr0[2], vr1[2];
  auto stageV_load = [&](int kbase) {
#pragma unroll
    for (int c = 0; c < 2; c++) {
      int task = tid + 256 * c;
      int vp = task >> 4, vc = task & 15;
      int r0 = kbase + 2 * vp;     if (r0 > 576) r0 = 576;
      int r1 = kbase + 2 * vp + 1; if (r1 > 576) r1 = 576;
      vr0[c] = *(const short4v*)(Vb + (baseHS + r0) * kd + 4 * vc);
      vr1[c] = *(const short4v*)(Vb + (baseHS + r1) * kd + 4 * vc);
    }
  };
  auto stageV_write = [&](short* dst) {
#pragma unroll
    for (int c = 0; c < 2; c++) {
      int task = tid + 256 * c;
      int vp = task >> 4, vc = task & 15;
      int kv2 = 2 * vp;
#pragma unroll
      for (int j = 0; j < 4; j++) {
        int d = 4 * vc + j;
        *(unsigned*)((char*)dst + d * 128 + ((kv2 * 2) ^ ((d & 7) << 4))) =
            (unsigned)(unsigned short)vr0[c][j] |
            ((unsigned)(unsigned short)vr1[c][j] << 16);
      }
    }
  };

  stageK(0, Klds[0]);
  stageV_load(0);
  stageV_write(Vlds[0]);
  __syncthreads();

  f32x16 o0 = {}, o1 = {};
  float m_run = -1e30f, l_run = 0.f;
  int cur = 0;
  const int NT = 10;

  for (int kt = 0; kt < NT; kt++) {
    int kbase = kt * 64;
    bool has_next = (kt + 1 < NT);
    if (has_next) {
      stageK(kbase + 64, Klds[cur ^ 1]);
      stageV_load(kbase + 64);
    }
    u32x4 pa[4];
    if (active) {
      const char* Kc = (const char*)Klds[cur];
      f32x16 st0 = {}, st1 = {};
      __builtin_amdgcn_s_setprio(1);
#pragma unroll
      for (int ks = 0; ks < 4; ks++) {
        int xr = ((2 * ks + hi) ^ (l31 & 7)) << 4;
        short8 k0 = *(const short8*)(Kc + l31 * 128 + xr);
        short8 k1 = *(const short8*)(Kc + (32 + l31) * 128 + xr);
        st0 = mfma32(k0, qf[ks], st0);
        st1 = mfma32(k1, qf[ks], st1);
      }
      __builtin_amdgcn_s_setprio(0);
      if (kbase + 64 > kS) {
#pragma unroll
        for (int r = 0; r < 16; r++) {
          int cr = (r & 3) + 8 * (r >> 2) + 4 * hi;
          if (kbase + cr > 576)      st0[r] = -1e30f;
          if (kbase + 32 + cr > 576) st1[r] = -1e30f;
        }
      }
      float mx = st0[0];
#pragma unroll
      for (int r = 0; r < 16; r++) {
        mx = fmaxf(mx, st0[r]);
        mx = fmaxf(mx, st1[r]);
      }
      mx = fmaxf(mx, __shfl_xor(mx, 32, 64));
      bool need = !__all(mx <= m_run + 8.0f);
      if (need) {
        float mnew = fmaxf(m_run, mx);
        float al = __expf(m_run - mnew);
        m_run = mnew;
        l_run *= al;
#pragma unroll
        for (int r = 0; r < 16; r++) {
          int cr = (r & 3) + 8 * (r >> 2) + 4 * hi;
          float ar = __shfl(al, cr, 64);
          o0[r] *= ar;
          o1[r] *= ar;
        }
      }
      float rs = 0.f;
#pragma unroll
      for (int r = 0; r < 16; r++) {
        float p0 = __expf(st0[r] - m_run); st0[r] = p0;
        float p1 = __expf(st1[r] - m_run); st1[r] = p1;
        rs += p0 + p1;
      }
      rs += __shfl_xor(rs, 32, 64);
      l_run += rs;
      {
        unsigned a0 = cvtpk(st0[0], st0[1]),   b0 = cvtpk(st0[4], st0[5]);   pl32(a0, b0);
        unsigned a1 = cvtpk(st0[2], st0[3]),   b1 = cvtpk(st0[6], st0[7]);   pl32(a1, b1);
        pa[0] = (u32x4){a0, a1, b0, b1};
        unsigned c0 = cvtpk(st0[8], st0[9]),   d0 = cvtpk(st0[12], st0[13]); pl32(c0, d0);
        unsigned c1 = cvtpk(st0[10], st0[11]), d1 = cvtpk(st0[14], st0[15]); pl32(c1, d1);
        pa[1] = (u32x4){c0, c1, d0, d1};
        unsigned e0 = cvtpk(st1[0], st1[1]),   f0 = cvtpk(st1[4], st1[5]);   pl32(e0, f0);
        unsigned e1 = cvtpk(st1[2], st1[3]),   f1 = cvtpk(st1[6], st1[7]);   pl32(e1, f1);
        pa[2] = (u32x4){e0, e1, f0, f1};
        unsigned g0 = cvtpk(st1[8], st1[9]),   h0 = cvtpk(st1[12], st1[13]); pl32(g0, h0);
        unsigned g1 = cvtpk(st1[10], st1[11]), h1 = cvtpk(st1[14], st1[15]); pl32(g1, h1);
        pa[3] = (u32x4){g0, g1, h0, h1};
      }
      const char* Vc = (const char*)Vlds[cur];
      __builtin_amdgcn_s_setprio(1);
#pragma unroll
      for (int ks = 0; ks < 4; ks++) {
        int xr = ((2 * ks + hi) ^ (l31 & 7)) << 4;
        short8 v0 = *(const short8*)(Vc + l31 * 128 + xr);
        short8 v1 = *(const short8*)(Vc + (32 + l31) * 128 + xr);
        o0 = mfma32(__builtin_bit_cast(short8, pa[ks]), v0, o0);
        o1 = mfma32(__builtin_bit_cast(short8, pa[ks]), v1, o1);
      }
      __builtin_amdgcn_s_setprio(0);
    }
    if (has_next) stageV_write(Vlds[cur ^ 1]);
    __syncthreads();
    cur ^= 1;
  }

  if (active) {
#pragma unroll
    for (int r = 0; r < 16; r++) {
      int cr = (r & 3) + 8 * (r >> 2) + 4 * hi;
      int qq = q0w + cr;
      if (qq < kS) {
        float lq = __shfl(l_run, cr, 64);
        float rl = 1.0f / lq;
        size_t gi = ((size_t)b * kS + qq) * kD + h * kd + l31;
        out[gi]      = x[gi]      + o0[r] * rl;
        out[gi + 32] = x[gi + 32] + o1[r] * rl;
      } else {
        (void)__shfl(l_run, cr, 64);
      }
    }
  }
}

// ======== GEMM1: 256x128xBK64, single-buffer 48KB LDS, 8 waves (4Mx2N), ========
// ======== launch_bounds(512,4) — winner config (~145us).                ========
__global__ __launch_bounds__(512, 4) void gemm_bb(const short* __restrict__ A,
                                                  const short* __restrict__ BT,
                                                  const float* __restrict__ bias,
                                                  short* __restrict__ outb,
                                                  float* __restrict__ outf,
                                                  int M, int N, int K, int mode) {
  __shared__ __align__(16) short As[256 * 64];  // 32 KiB
  __shared__ __align__(16) short Bs[128 * 64];  // 16 KiB

  int nwg = gridDim.x, bid = blockIdx.x;
  int q = nwg >> 3, r = nwg & 7;
  int xcd = bid & 7, lx = bid >> 3;
  int swz = (xcd < r ? xcd * (q + 1) : r * (q + 1) + (xcd - r) * q) + lx;
  int gn = N >> 7;
  int nt = swz % gn, mt = swz / gn;
  int m0 = mt << 8, n0 = nt << 7;

  int tid = threadIdx.x;
  int w = tid >> 6, l = tid & 63, l15 = l & 15, l4 = l >> 4;
  int wm = w >> 1, wn = w & 1;

  int srow = tid >> 3;
  int sslot = (tid & 7) ^ (srow & 7);
  int sdst = (tid & ~63) * 8;
  const short* Asrc = A + (size_t)(m0 + srow) * K + sslot * 8;
  const short* Bsrc = BT + (size_t)(n0 + srow) * K + sslot * 8;

  const char* ldsA = (const char*)As + wm * 8192;
  const char* ldsB = (const char*)Bs + wn * 8192;

  f32x4 acc[4][4] = {};

  for (int k0 = 0; k0 < K; k0 += 64) {
    __syncthreads();
#pragma unroll
    for (int i = 0; i < 4; i++)
      load_lds16(Asrc + (size_t)(64 * i) * K + k0, As + i * 4096 + sdst);
#pragma unroll
    for (int j = 0; j < 2; j++)
      load_lds16(Bsrc + (size_t)(64 * j) * K + k0, Bs + j * 4096 + sdst);
    __syncthreads();
#pragma unroll
    for (int kk = 0; kk < 2; kk++) {
      short8 aF[4], bF[4];
#pragma unroll
      for (int i = 0; i < 4; i++) {
        int ra = 16 * i + l15;
        aF[i] = *(const short8*)(ldsA + ra * 128 + (((kk * 4 + l4) ^ (ra & 7)) << 4));
        bF[i] = *(const short8*)(ldsB + ra * 128 + (((kk * 4 + l4) ^ (ra & 7)) << 4));
      }
#pragma unroll
      for (int i = 0; i < 4; i++)
#pragma unroll
        for (int j = 0; j < 4; j++)
          acc[i][j] = mfma16(aF[i], bF[j], acc[i][j]);
    }
  }

#pragma unroll
  for (int i = 0; i < 4; i++) {
#pragma unroll
    for (int j = 0; j < 4; j++) {
      int col = n0 + wn * 64 + 16 * j + l15;
      float bs = bias[col];
#pragma unroll
      for (int rr = 0; rr < 4; rr++) {
        int row = m0 + wm * 64 + 16 * i + 4 * l4 + rr;
        if (row >= M) continue;
        float v = acc[i][j][rr] + bs;
        if (mode == 0) {
          outb[(size_t)row * N + col] = f2bf(gelu_f(v));
        } else {
          outf[(size_t)row * N + col] += v;
        }
      }
    }
  }
}

// ======== GEMM2: 128x128xBK64 drain loop, 32KB LDS, (256,4) — R10 winner ========
__global__ __launch_bounds__(256, 4) void gemm2b(const short* __restrict__ A,
                                                 const short* __restrict__ BT,
                                                 const float* __restrict__ bias,
                                                 float* __restrict__ outf,
                                                 int M, int N, int K) {
  __shared__ __align__(16) short As[128 * 64];  // 16 KiB
  __shared__ __align__(16) short Bs[128 * 64];  // 16 KiB

  int nwg = gridDim.x, bid = blockIdx.x;
  int q = nwg >> 3, r = nwg & 7;
  int xcd = bid & 7, lx = bid >> 3;
  int swz = (xcd < r ? xcd * (q + 1) : r * (q + 1) + (xcd - r) * q) + lx;
  int gn = N >> 7;  // 6
  int nt = swz % gn, mt = swz / gn;
  int m0 = mt << 7, n0 = nt << 7;

  int tid = threadIdx.x;
  int w = tid >> 6, l = tid & 63, l15 = l & 15, l4 = l >> 4;
  int wm = w >> 1, wn = w & 1;

  int srow = tid >> 3;                     // 0..31
  int sslot = (tid & 7) ^ (srow & 7);
  int sdst = (tid & ~63) * 8;              // wave-uniform dest (shorts)
  const short* Asrc = A + (size_t)(m0 + srow) * K + sslot * 8;
  const short* Bsrc = BT + (size_t)(n0 + srow) * K + sslot * 8;

  const char* ldsA = (const char*)As + wm * 8192;
  const char* ldsB = (const char*)Bs + wn * 8192;

  f32x4 acc[4][4] = {};

  for (int k0 = 0; k0 < K; k0 += 64) {
    __syncthreads();
#pragma unroll
    for (int i = 0; i < 4; i++)
      load_lds16(Asrc + (size_t)(32 * i) * K + k0, As + i * 2048 + sdst);
#pragma unroll
    for (int j = 0; j < 4; j++)
      load_lds16(Bsrc + (size_t)(32 * j) * K + k0, Bs + j * 2048 + sdst);
    __syncthreads();
#pragma unroll
    for (int kk = 0; kk < 2; kk++) {
      short8 aF[4], bF[4];
#pragma unroll
      for (int i = 0; i < 4; i++) {
        int ra = 16 * i + l15;
        aF[i] = *(const short8*)(ldsA + ra * 128 + (((kk * 4 + l4) ^ (ra & 7)) << 4));
        bF[i] = *(const short8*)(ldsB + ra * 128 + (((kk * 4 + l4) ^ (ra & 7)) << 4));
      }
#pragma unroll
      for (int i = 0; i < 4; i++)
#pragma unroll
        for (int j = 0; j < 4; j++)
          acc[i][j] = mfma16(aF[i], bF[j], acc[i][j]);
    }
  }

#pragma unroll
  for (int i = 0; i < 4; i++) {
#pragma unroll
    for (int j = 0; j < 4; j++) {
      int col = n0 + wn * 64 + 16 * j + l15;
      float bs = bias[col];
#pragma unroll
      for (int rr = 0; rr < 4; rr++) {
        int row = m0 + wm * 64 + 16 * i + 4 * l4 + rr;
        if (row >= M) continue;
        outf[(size_t)row * N + col] += acc[i][j][rr] + bs;
      }
    }
  }
}

extern "C" void kernel_launch(void* const* d_in, const int* in_sizes, int n_in,
                              void* d_out, int out_size, void* d_ws, size_t ws_size,
                              hipStream_t stream) {
  const float* x     = (const float*)d_in[0];
  const float* ln1_g = (const float*)d_in[1];
  const float* ln1_b = (const float*)d_in[2];
  const float* Wq    = (const float*)d_in[3];
  const float* bq    = (const float*)d_in[4];
  const float* Wk    = (const float*)d_in[5];
  const float* bk    = (const float*)d_in[6];
  const float* Wv    = (const float*)d_in[7];
  const float* bv    = (const float*)d_in[8];
  const float* ln2_g = (const float*)d_in[9];
  const float* ln2_b = (const float*)d_in[10];
  const float* W1    = (const float*)d_in[11];
  const float* b1    = (const float*)d_in[12];
  const float* W2    = (const float*)d_in[13];
  const float* b2    = (const float*)d_in[14];
  float* out = (float*)d_out;

  char* ws = (char*)d_ws;
  size_t off = 0;
  auto alloc = [&](size_t bytes) {
    size_t o = off;
    off += (bytes + 255) & ~(size_t)255;
    return o;
  };
  short* xn    = (short*)(ws + alloc((size_t)kTOK * kD * 2));
  short* wqkvT = (short*)(ws + alloc((size_t)kH * 192 * kd * 2));
  short* w1T   = (short*)(ws + alloc((size_t)kMLP * kD * 2));
  short* w2T   = (short*)(ws + alloc((size_t)kD * kMLP * 2));
  short* Qb    = (short*)(ws + alloc((size_t)kTOK * kD * 2));
  short* Kb    = (short*)(ws + alloc((size_t)kTOK * kD * 2));
  short* Vb    = (short*)(ws + alloc((size_t)kTOK * kD * 2));
  short* hbuf  = (short*)(ws + alloc((size_t)kMPAD * kD * 2));
  short* gbuf  = (short*)(ws + alloc((size_t)kMPAD * kMLP * 2));

  ln_prep<<<kTOK / 4 + 1728, 256, 0, stream>>>(
      x, ln1_g, ln1_b, xn, W1, W2, Wq, Wk, Wv, w1T, w2T, wqkvT);
  qkv_gemm<<<dim3((kTOK + 127) / 128, kH), 384, 0, stream>>>(
      xn, wqkvT, bq, bk, bv, Qb, Kb, Vb);
  attn_kernel<<<5 * kH * kB, 256, 0, stream>>>(Qb, Kb, Vb, x, out);
  ln_kernel<<<kTOK / 4, 256, 0, stream>>>(out, ln2_g, ln2_b, hbuf);
  gemm_bb<<<(kMPAD / 256) * (kMLP / 128), 512, 0, stream>>>(
      hbuf, w1T, b1, gbuf, nullptr, kTOK, kMLP, kD, 0);
  gemm2b<<<(kMPAD / 128) * (kD / 128), 256, 0, stream>>>(
      gbuf, w2T, b2, out, kTOK, kD, kMLP);
}

// Round 20
// 442.032 us; speedup vs baseline: 3.2180x; 1.0180x over previous
//
#include <hip/hip_runtime.h>
#include <hip/hip_bf16.h>

// ViT transformer block: B=32 S=577 D=768 H=12 d=64 MLP=3072, f32 in/out.
// R20: LN passes widened to 8 rows/block (512 thr) — fewer blocks on the two
//      BW-bound passes; qkv epilogue div hoisted. All else = R19 (450.0us).
//      GEMM pair is register-budget-pinned (see R17 ledger); attention
//      implements the m214 recipe. This is the structural plateau config.

#define kB   32
#define kS   577
#define kD   768
#define kH   12
#define kd   64
#define kMLP 3072
#define kTOK (kB * kS)   // 18464
#define kMPAD 18688      // 73 * 256 = 146 * 128

typedef short short8 __attribute__((ext_vector_type(8)));
typedef short short4v __attribute__((ext_vector_type(4)));
typedef float f32x4 __attribute__((ext_vector_type(4)));
typedef float f32x16 __attribute__((ext_vector_type(16)));
typedef unsigned u32x4 __attribute__((ext_vector_type(4)));
typedef __bf16 bf16x8 __attribute__((ext_vector_type(8)));

__device__ inline short f2bf(float f) {
  unsigned u = __float_as_uint(f);
  unsigned r = (u + 0x7FFFu + ((u >> 16) & 1u)) >> 16;
  return (short)r;
}

__device__ inline f32x4 mfma16(short8 a, short8 b, f32x4 c) {
  return __builtin_amdgcn_mfma_f32_16x16x32_bf16(
      __builtin_bit_cast(bf16x8, a), __builtin_bit_cast(bf16x8, b), c, 0, 0, 0);
}

__device__ inline f32x16 mfma32(short8 a, short8 b, f32x16 c) {
  return __builtin_amdgcn_mfma_f32_32x32x16_bf16(
      __builtin_bit_cast(bf16x8, a), __builtin_bit_cast(bf16x8, b), c, 0, 0, 0);
}

__device__ inline void load_lds16(const short* g, short* l) {
  __builtin_amdgcn_global_load_lds(
      (__attribute__((address_space(1))) void*)(g),
      (__attribute__((address_space(3))) void*)(l), 16, 0, 0);
}

__device__ inline unsigned cvtpk(float lo, float hi) {
  unsigned r;
  asm("v_cvt_pk_bf16_f32 %0, %1, %2" : "=v"(r) : "v"(lo), "v"(hi));
  return r;
}

__device__ inline void pl32(unsigned &a, unsigned &b) {
  typedef int int2v __attribute__((ext_vector_type(2)));
  int2v r = __builtin_amdgcn_permlane32_swap((int)a, (int)b, false, false);
  a = (unsigned)r[0];
  b = (unsigned)r[1];
}

// NaN-safe tanh-GELU (max dev from exact erf-GELU ~4e-4)
__device__ inline float gelu_f(float x) {
  float u = x * x;
  float z = x * fmaf(0.0713548162f, u, 1.5957691216f);
  float e = __expf(z);
  return x - x / (e + 1.0f);
}

// ---- LN body: one wave normalizes one row (l = lane) ----
__device__ inline void ln_row(const float* __restrict__ x,
                              const float* __restrict__ g,
                              const float* __restrict__ b,
                              short* __restrict__ out, int row, int l) {
  const float* xr = x + (size_t)row * kD + l * 12;
  f32x4 v0 = *(const f32x4*)(xr);
  f32x4 v1 = *(const f32x4*)(xr + 4);
  f32x4 v2 = *(const f32x4*)(xr + 8);
  float s = 0.f, ss = 0.f;
#pragma unroll
  for (int j = 0; j < 4; j++) {
    s += v0[j] + v1[j] + v2[j];
    ss += v0[j] * v0[j] + v1[j] * v1[j] + v2[j] * v2[j];
  }
#pragma unroll
  for (int off = 1; off < 64; off <<= 1) {
    s += __shfl_xor(s, off, 64);
    ss += __shfl_xor(ss, off, 64);
  }
  float mean = s * (1.f / kD);
  float var = ss * (1.f / kD) - mean * mean;
  float rstd = rsqrtf(var + 1e-5f);
  const float* gr = g + l * 12;
  const float* br = b + l * 12;
  f32x4 g0 = *(const f32x4*)(gr), g1 = *(const f32x4*)(gr + 4),
        g2 = *(const f32x4*)(gr + 8);
  f32x4 b0 = *(const f32x4*)(br), b1 = *(const f32x4*)(br + 4),
        b2 = *(const f32x4*)(br + 8);
  short4v r0, r1, r2;
#pragma unroll
  for (int j = 0; j < 4; j++) {
    r0[j] = f2bf((v0[j] - mean) * rstd * g0[j] + b0[j]);
    r1[j] = f2bf((v1[j] - mean) * rstd * g1[j] + b1[j]);
    r2[j] = f2bf((v2[j] - mean) * rstd * g2[j] + b2[j]);
  }
  short* o = out + (size_t)row * kD + l * 12;
  *(short4v*)(o) = r0;
  *(short4v*)(o + 4) = r1;
  *(short4v*)(o + 8) = r2;
}

// ------- LayerNorm (standalone, for LN2): 8 rows/block, 512 threads -------
__global__ __launch_bounds__(512) void ln_kernel(const float* __restrict__ x,
                                                 const float* __restrict__ g,
                                                 const float* __restrict__ b,
                                                 short* __restrict__ out) {
  ln_row(x, g, b, out, blockIdx.x * 8 + (threadIdx.x >> 6), threadIdx.x & 63);
}

// ---- 64x64 transpose tile helper (f32 in -> bf16 out, transposed) ----
// 512 threads: 8 rows per pass-slot.
__device__ inline void tr_tile(const float* __restrict__ in, short* __restrict__ out,
                               int R, int C, int c0, int r0) {
  __shared__ short tile[64][66];
  int t = threadIdx.x;
  int c = t & 63, rr = t >> 6;
#pragma unroll
  for (int p = 0; p < 8; p++) {
    int r = p * 8 + rr;
    tile[r][c] = f2bf(in[(size_t)(r0 + r) * C + c0 + c]);
  }
  __syncthreads();
  int r2 = t & 63, cc = t >> 6;
#pragma unroll
  for (int p = 0; p < 8; p++) {
    int c2 = p * 8 + cc;
    out[(size_t)(c0 + c2) * R + r0 + r2] = tile[r2][c2];
  }
}

// ---- fused LN1 + weight prep (512 threads/block) ----
// blocks [0, kTOK/8): LN1 8 rows each; then 576 W1 tiles, 576 W2 tiles,
// 288 QKV-pack blocks (512 elems each... 288*512*... ) -> see ranges below.
__global__ __launch_bounds__(512) void ln_prep(const float* __restrict__ x,
                                               const float* __restrict__ ln1_g,
                                               const float* __restrict__ ln1_b,
                                               short* __restrict__ xn,
                                               const float* __restrict__ W1,
                                               const float* __restrict__ W2,
                                               const float* __restrict__ Wq,
                                               const float* __restrict__ Wk,
                                               const float* __restrict__ Wv,
                                               short* __restrict__ w1T,
                                               short* __restrict__ w2T,
                                               short* __restrict__ wqkvT) {
  int bid = blockIdx.x;
  if (bid < kTOK / 8) {                  // LN1: 8 rows per block
    ln_row(x, ln1_g, ln1_b, xn, bid * 8 + (threadIdx.x >> 6), threadIdx.x & 63);
    return;
  }
  bid -= kTOK / 8;
  if (bid < 576) {                       // W1 [kD][kMLP] -> w1T [kMLP][kD]
    int bx = bid % (kMLP / 64), by = bid / (kMLP / 64);
    tr_tile(W1, w1T, kD, kMLP, bx * 64, by * 64);
  } else if (bid < 1152) {               // W2 [kMLP][kD] -> w2T [kD][kMLP]
    int b2 = bid - 576;
    int bx = b2 % (kD / 64), by = b2 / (kD / 64);
    tr_tile(W2, w2T, kMLP, kD, bx * 64, by * 64);
  } else {                               // pack Wq/Wk/Wv -> wqkvT[h][192][64]
    int idx = (bid - 1152) * 512 + threadIdx.x;   // 288 blocks * 512 = 147456
    int h = idx / (192 * kd);
    int j = (idx / kd) % 192;
    int k = idx % kd;
    int m = j >> 6, e = j & 63;
    const float* W = (m == 0) ? Wq : (m == 1) ? Wk : Wv;
    wqkvT[idx] = f2bf(W[((size_t)h * kd + k) * kd + e]);
  }
}

// ---- QKV GEMM: 128-token tile x head; 6 waves = 2 token-halves x {Q,K,V} ----
// Q output pre-scaled by 1/8 (= 1/sqrt(64)).
__global__ __launch_bounds__(384) void qkv_gemm(const short* __restrict__ xn,
                                                const short* __restrict__ wt,
                                                const float* __restrict__ bq,
                                                const float* __restrict__ bk,
                                                const float* __restrict__ bv,
                                                short* __restrict__ Qb,
                                                short* __restrict__ Kb,
                                                short* __restrict__ Vb) {
  int t0 = blockIdx.x * 128;
  int h = blockIdx.y;
  __shared__ __align__(16) short As[128][72];
  __shared__ __align__(16) short Bs[192][72];
  int tid = threadIdx.x;
  for (int c = tid; c < 128 * 8; c += 384) {
    int row = c >> 3, c8 = c & 7;
    short8 v = {};
    int tok = t0 + row;
    if (tok < kTOK) v = *(const short8*)(xn + (size_t)tok * kD + h * kd + c8 * 8);
    *(short8*)&As[row][c8 * 8] = v;
  }
  const short* wth = wt + (size_t)h * 192 * kd;
  for (int c = tid; c < 192 * 8; c += 384) {
    int row = c >> 3, c8 = c & 7;
    *(short8*)&Bs[row][c8 * 8] = *(const short8*)(wth + row * kd + c8 * 8);
  }
  __syncthreads();
  int w = tid >> 6, l = tid & 63, l15 = l & 15, l4 = l >> 4;
  int m = w % 3;            // 0=Q 1=K 2=V
  int half = w / 3;         // token half (0/1)
  f32x4 acc[4][4] = {};
  short8 aF[4][2], bF[4][2];
#pragma unroll
  for (int rf = 0; rf < 4; rf++)
#pragma unroll
    for (int kk = 0; kk < 2; kk++)
      aF[rf][kk] = *(const short8*)&As[half * 64 + 16 * rf + l15][32 * kk + 8 * l4];
#pragma unroll
  for (int cf = 0; cf < 4; cf++)
#pragma unroll
    for (int kk = 0; kk < 2; kk++)
      bF[cf][kk] = *(const short8*)&Bs[m * 64 + 16 * cf + l15][32 * kk + 8 * l4];
#pragma unroll
  for (int rf = 0; rf < 4; rf++)
#pragma unroll
    for (int cf = 0; cf < 4; cf++) {
      f32x4 c = acc[rf][cf];
      c = mfma16(aF[rf][0], bF[cf][0], c);
      c = mfma16(aF[rf][1], bF[cf][1], c);
      acc[rf][cf] = c;
    }
  const float* bias = (m == 0) ? bq : (m == 1) ? bk : bv;
  short* Out = (m == 0) ? Qb : (m == 1) ? Kb : Vb;
  float scale = (m == 0) ? 0.125f : 1.0f;
#pragma unroll
  for (int rf = 0; rf < 4; rf++) {
#pragma unroll
    for (int r = 0; r < 4; r++) {
      int tok = t0 + half * 64 + 16 * rf + 4 * l4 + r;
      if (tok >= kTOK) continue;
      int bb = tok / kS, ssi = tok % kS;          // hoisted out of cf loop
      size_t base = (((size_t)bb * kH + h) * kS + ssi) * kd;
#pragma unroll
      for (int cf = 0; cf < 4; cf++) {
        int col = 16 * cf + l15;
        Out[base + col] = f2bf((acc[rf][cf][r] + bias[h * kd + col]) * scale);
      }
    }
  }
}

// -------- flash attention, swapped-QK^T 32x32 structure; fuses out = x + attn --------
__global__ __launch_bounds__(256) void attn_kernel(const short* __restrict__ Qb,
                                                   const short* __restrict__ Kb,
                                                   const short* __restrict__ Vb,
                                                   const float* __restrict__ x,
                                                   float* __restrict__ out) {
  int nwg = gridDim.x;                    // 1920
  int bid = blockIdx.x;
  int chunk = nwg >> 3;                   // 240
  int swz = (bid & 7) * chunk + (bid >> 3);
  int qt = swz % 5;
  int bh = swz / 5;
  int h = bh % kH;
  int b = bh / kH;
  const size_t baseHS = ((size_t)b * kH + h) * kS;
  __shared__ __align__(16) short Klds[2][64 * 64];
  __shared__ __align__(16) short Vlds[2][64 * 64];
  int tid = threadIdx.x;
  int w = tid >> 6, l = tid & 63;
  int l31 = l & 31, hi = l >> 5;
  int q0w = qt * 128 + w * 32;
  bool active = (q0w < kS);

  int qg = q0w + l31;
  const short* qp = Qb + (baseHS + (qg > 576 ? 576 : qg)) * kd + 8 * hi;
  short8 qf[4];
#pragma unroll
  for (int ks = 0; ks < 4; ks++) qf[ks] = *(const short8*)(qp + 16 * ks);

  auto stageK = [&](int kbase, short* dst) {
#pragma unroll
    for (int c = 0; c < 2; c++) {
      int chnk = tid + 256 * c;
      int row = chnk >> 3, sl = chnk & 7;
      int sr = kbase + row; if (sr > 576) sr = 576;
      load_lds16(Kb + (baseHS + sr) * kd + 8 * (sl ^ (row & 7)),
                 dst + (chnk & ~63) * 8);
    }
  };
  short4v vr0[2], vr1[2];
  auto stageV_load = [&](int kbase) {
#pragma unroll
    for (int c = 0; c < 2; c++) {
      int task = tid + 256 * c;
      int vp = task >> 4, vc = task & 15;
      int r0 = kbase + 2 * vp;     if (r0 > 576) r0 = 576;
      int r1 = kbase + 2 * vp + 1; if (r1 > 576) r1 = 576;
      vr0[c] = *(const short4v*)(Vb + (baseHS + r0) * kd + 4 * vc);
      vr1[c] = *(const short4v*)(Vb + (baseHS + r1) * kd + 4 * vc);
    }
  };
  auto stageV_write = [&](short* dst) {
#pragma unroll
    for (int c = 0; c < 2; c++) {
      int task = tid + 256 * c;
      int vp = task >> 4, vc = task & 15;
      int kv2 = 2 * vp;
#pragma unroll
      for (int j = 0; j < 4; j++) {
        int d = 4 * vc + j;
        *(unsigned*)((char*)dst + d * 128 + ((kv2 * 2) ^ ((d & 7) << 4))) =
            (unsigned)(unsigned short)vr0[c][j] |
            ((unsigned)(unsigned short)vr1[c][j] << 16);
      }
    }
  };

  stageK(0, Klds[0]);
  stageV_load(0);
  stageV_write(Vlds[0]);
  __syncthreads();

  f32x16 o0 = {}, o1 = {};
  float m_run = -1e30f, l_run = 0.f;
  int cur = 0;
  const int NT = 10;

  for (int kt = 0; kt < NT; kt++) {
    int kbase = kt * 64;
    bool has_next = (kt + 1 < NT);
    if (has_next) {
      stageK(kbase + 64, Klds[cur ^ 1]);
      stageV_load(kbase + 64);
    }
    u32x4 pa[4];
    if (active) {
      const char* Kc = (const char*)Klds[cur];
      f32x16 st0 = {}, st1 = {};
      __builtin_amdgcn_s_setprio(1);
#pragma unroll
      for (int ks = 0; ks < 4; ks++) {
        int xr = ((2 * ks + hi) ^ (l31 & 7)) << 4;
        short8 k0 = *(const short8*)(Kc + l31 * 128 + xr);
        short8 k1 = *(const short8*)(Kc + (32 + l31) * 128 + xr);
        st0 = mfma32(k0, qf[ks], st0);
        st1 = mfma32(k1, qf[ks], st1);
      }
      __builtin_amdgcn_s_setprio(0);
      if (kbase + 64 > kS) {
#pragma unroll
        for (int r = 0; r < 16; r++) {
          int cr = (r & 3) + 8 * (r >> 2) + 4 * hi;
          if (kbase + cr > 576)      st0[r] = -1e30f;
          if (kbase + 32 + cr > 576) st1[r] = -1e30f;
        }
      }
      float mx = st0[0];
#pragma unroll
      for (int r = 0; r < 16; r++) {
        mx = fmaxf(mx, st0[r]);
        mx = fmaxf(mx, st1[r]);
      }
      mx = fmaxf(mx, __shfl_xor(mx, 32, 64));
      bool need = !__all(mx <= m_run + 8.0f);
      if (need) {
        float mnew = fmaxf(m_run, mx);
        float al = __expf(m_run - mnew);
        m_run = mnew;
        l_run *= al;
#pragma unroll
        for (int r = 0; r < 16; r++) {
          int cr = (r & 3) + 8 * (r >> 2) + 4 * hi;
          float ar = __shfl(al, cr, 64);
          o0[r] *= ar;
          o1[r] *= ar;
        }
      }
      float rs = 0.f;
#pragma unroll
      for (int r = 0; r < 16; r++) {
        float p0 = __expf(st0[r] - m_run); st0[r] = p0;
        float p1 = __expf(st1[r] - m_run); st1[r] = p1;
        rs += p0 + p1;
      }
      rs += __shfl_xor(rs, 32, 64);
      l_run += rs;
      {
        unsigned a0 = cvtpk(st0[0], st0[1]),   b0 = cvtpk(st0[4], st0[5]);   pl32(a0, b0);
        unsigned a1 = cvtpk(st0[2], st0[3]),   b1 = cvtpk(st0[6], st0[7]);   pl32(a1, b1);
        pa[0] = (u32x4){a0, a1, b0, b1};
        unsigned c0 = cvtpk(st0[8], st0[9]),   d0 = cvtpk(st0[12], st0[13]); pl32(c0, d0);
        unsigned c1 = cvtpk(st0[10], st0[11]), d1 = cvtpk(st0[14], st0[15]); pl32(c1, d1);
        pa[1] = (u32x4){c0, c1, d0, d1};
        unsigned e0 = cvtpk(st1[0], st1[1]),   f0 = cvtpk(st1[4], st1[5]);   pl32(e0, f0);
        unsigned e1 = cvtpk(st1[2], st1[3]),   f1 = cvtpk(st1[6], st1[7]);   pl32(e1, f1);
        pa[2] = (u32x4){e0, e1, f0, f1};
        unsigned g0 = cvtpk(st1[8], st1[9]),   h0 = cvtpk(st1[12], st1[13]); pl32(g0, h0);
        unsigned g1 = cvtpk(st1[10], st1[11]), h1 = cvtpk(st1[14], st1[15]); pl32(g1, h1);
        pa[3] = (u32x4){g0, g1, h0, h1};
      }
      const char* Vc = (const char*)Vlds[cur];
      __builtin_amdgcn_s_setprio(1);
#pragma unroll
      for (int ks = 0; ks < 4; ks++) {
        int xr = ((2 * ks + hi) ^ (l31 & 7)) << 4;
        short8 v0 = *(const short8*)(Vc + l31 * 128 + xr);
        short8 v1 = *(const short8*)(Vc + (32 + l31) * 128 + xr);
        o0 = mfma32(__builtin_bit_cast(short8, pa[ks]), v0, o0);
        o1 = mfma32(__builtin_bit_cast(short8, pa[ks]), v1, o1);
      }
      __builtin_amdgcn_s_setprio(0);
    }
    if (has_next) stageV_write(Vlds[cur ^ 1]);
    __syncthreads();
    cur ^= 1;
  }

  if (active) {
#pragma unroll
    for (int r = 0; r < 16; r++) {
      int cr = (r & 3) + 8 * (r >> 2) + 4 * hi;
      int qq = q0w + cr;
      if (qq < kS) {
        float lq = __shfl(l_run, cr, 64);
        float rl = 1.0f / lq;
        size_t gi = ((size_t)b * kS + qq) * kD + h * kd + l31;
        out[gi]      = x[gi]      + o0[r] * rl;
        out[gi + 32] = x[gi + 32] + o1[r] * rl;
      } else {
        (void)__shfl(l_run, cr, 64);
      }
    }
  }
}

// ======== GEMM1: 256x128xBK64, single-buffer 48KB LDS, 8 waves (4Mx2N), ========
// ======== launch_bounds(512,4) — winner config (~145us).                ========
__global__ __launch_bounds__(512, 4) void gemm_bb(const short* __restrict__ A,
                                                  const short* __restrict__ BT,
                                                  const float* __restrict__ bias,
                                                  short* __restrict__ outb,
                                                  float* __restrict__ outf,
                                                  int M, int N, int K, int mode) {
  __shared__ __align__(16) short As[256 * 64];  // 32 KiB
  __shared__ __align__(16) short Bs[128 * 64];  // 16 KiB

  int nwg = gridDim.x, bid = blockIdx.x;
  int q = nwg >> 3, r = nwg & 7;
  int xcd = bid & 7, lx = bid >> 3;
  int swz = (xcd < r ? xcd * (q + 1) : r * (q + 1) + (xcd - r) * q) + lx;
  int gn = N >> 7;
  int nt = swz % gn, mt = swz / gn;
  int m0 = mt << 8, n0 = nt << 7;

  int tid = threadIdx.x;
  int w = tid >> 6, l = tid & 63, l15 = l & 15, l4 = l >> 4;
  int wm = w >> 1, wn = w & 1;

  int srow = tid >> 3;
  int sslot = (tid & 7) ^ (srow & 7);
  int sdst = (tid & ~63) * 8;
  const short* Asrc = A + (size_t)(m0 + srow) * K + sslot * 8;
  const short* Bsrc = BT + (size_t)(n0 + srow) * K + sslot * 8;

  const char* ldsA = (const char*)As + wm * 8192;
  const char* ldsB = (const char*)Bs + wn * 8192;

  f32x4 acc[4][4] = {};

  for (int k0 = 0; k0 < K; k0 += 64) {
    __syncthreads();
#pragma unroll
    for (int i = 0; i < 4; i++)
      load_lds16(Asrc + (size_t)(64 * i) * K + k0, As + i * 4096 + sdst);
#pragma unroll
    for (int j = 0; j < 2; j++)
      load_lds16(Bsrc + (size_t)(64 * j) * K + k0, Bs + j * 4096 + sdst);
    __syncthreads();
#pragma unroll
    for (int kk = 0; kk < 2; kk++) {
      short8 aF[4], bF[4];
#pragma unroll
      for (int i = 0; i < 4; i++) {
        int ra = 16 * i + l15;
        aF[i] = *(const short8*)(ldsA + ra * 128 + (((kk * 4 + l4) ^ (ra & 7)) << 4));
        bF[i] = *(const short8*)(ldsB + ra * 128 + (((kk * 4 + l4) ^ (ra & 7)) << 4));
      }
#pragma unroll
      for (int i = 0; i < 4; i++)
#pragma unroll
        for (int j = 0; j < 4; j++)
          acc[i][j] = mfma16(aF[i], bF[j], acc[i][j]);
    }
  }

#pragma unroll
  for (int i = 0; i < 4; i++) {
#pragma unroll
    for (int j = 0; j < 4; j++) {
      int col = n0 + wn * 64 + 16 * j + l15;
      float bs = bias[col];
#pragma unroll
      for (int rr = 0; rr < 4; rr++) {
        int row = m0 + wm * 64 + 16 * i + 4 * l4 + rr;
        if (row >= M) continue;
        float v = acc[i][j][rr] + bs;
        if (mode == 0) {
          outb[(size_t)row * N + col] = f2bf(gelu_f(v));
        } else {
          outf[(size_t)row * N + col] += v;
        }
      }
    }
  }
}

// ======== GEMM2: 128x128xBK64 drain loop, 32KB LDS, (256,4) — R10 winner ========
__global__ __launch_bounds__(256, 4) void gemm2b(const short* __restrict__ A,
                                                 const short* __restrict__ BT,
                                                 const float* __restrict__ bias,
                                                 float* __restrict__ outf,
                                                 int M, int N, int K) {
  __shared__ __align__(16) short As[128 * 64];  // 16 KiB
  __shared__ __align__(16) short Bs[128 * 64];  // 16 KiB

  int nwg = gridDim.x, bid = blockIdx.x;
  int q = nwg >> 3, r = nwg & 7;
  int xcd = bid & 7, lx = bid >> 3;
  int swz = (xcd < r ? xcd * (q + 1) : r * (q + 1) + (xcd - r) * q) + lx;
  int gn = N >> 7;  // 6
  int nt = swz % gn, mt = swz / gn;
  int m0 = mt << 7, n0 = nt << 7;

  int tid = threadIdx.x;
  int w = tid >> 6, l = tid & 63, l15 = l & 15, l4 = l >> 4;
  int wm = w >> 1, wn = w & 1;

  int srow = tid >> 3;                     // 0..31
  int sslot = (tid & 7) ^ (srow & 7);
  int sdst = (tid & ~63) * 8;              // wave-uniform dest (shorts)
  const short* Asrc = A + (size_t)(m0 + srow) * K + sslot * 8;
  const short* Bsrc = BT + (size_t)(n0 + srow) * K + sslot * 8;

  const char* ldsA = (const char*)As + wm * 8192;
  const char* ldsB = (const char*)Bs + wn * 8192;

  f32x4 acc[4][4] = {};

  for (int k0 = 0; k0 < K; k0 += 64) {
    __syncthreads();
#pragma unroll
    for (int i = 0; i < 4; i++)
      load_lds16(Asrc + (size_t)(32 * i) * K + k0, As + i * 2048 + sdst);
#pragma unroll
    for (int j = 0; j < 4; j++)
      load_lds16(Bsrc + (size_t)(32 * j) * K + k0, Bs + j * 2048 + sdst);
    __syncthreads();
#pragma unroll
    for (int kk = 0; kk < 2; kk++) {
      short8 aF[4], bF[4];
#pragma unroll
      for (int i = 0; i < 4; i++) {
        int ra = 16 * i + l15;
        aF[i] = *(const short8*)(ldsA + ra * 128 + (((kk * 4 + l4) ^ (ra & 7)) << 4));
        bF[i] = *(const short8*)(ldsB + ra * 128 + (((kk * 4 + l4) ^ (ra & 7)) << 4));
      }
#pragma unroll
      for (int i = 0; i < 4; i++)
#pragma unroll
        for (int j = 0; j < 4; j++)
          acc[i][j] = mfma16(aF[i], bF[j], acc[i][j]);
    }
  }

#pragma unroll
  for (int i = 0; i < 4; i++) {
#pragma unroll
    for (int j = 0; j < 4; j++) {
      int col = n0 + wn * 64 + 16 * j + l15;
      float bs = bias[col];
#pragma unroll
      for (int rr = 0; rr < 4; rr++) {
        int row = m0 + wm * 64 + 16 * i + 4 * l4 + rr;
        if (row >= M) continue;
        outf[(size_t)row * N + col] += acc[i][j][rr] + bs;
      }
    }
  }
}

extern "C" void kernel_launch(void* const* d_in, const int* in_sizes, int n_in,
                              void* d_out, int out_size, void* d_ws, size_t ws_size,
                              hipStream_t stream) {
  const float* x     = (const float*)d_in[0];
  const float* ln1_g = (const float*)d_in[1];
  const float* ln1_b = (const float*)d_in[2];
  const float* Wq    = (const float*)d_in[3];
  const float* bq    = (const float*)d_in[4];
  const float* Wk    = (const float*)d_in[5];
  const float* bk    = (const float*)d_in[6];
  const float* Wv    = (const float*)d_in[7];
  const float* bv    = (const float*)d_in[8];
  const float* ln2_g = (const float*)d_in[9];
  const float* ln2_b = (const float*)d_in[10];
  const float* W1    = (const float*)d_in[11];
  const float* b1    = (const float*)d_in[12];
  const float* W2    = (const float*)d_in[13];
  const float* b2    = (const float*)d_in[14];
  float* out = (float*)d_out;

  char* ws = (char*)d_ws;
  size_t off = 0;
  auto alloc = [&](size_t bytes) {
    size_t o = off;
    off += (bytes + 255) & ~(size_t)255;
    return o;
  };
  short* xn    = (short*)(ws + alloc((size_t)kTOK * kD * 2));
  short* wqkvT = (short*)(ws + alloc((size_t)kH * 192 * kd * 2));
  short* w1T   = (short*)(ws + alloc((size_t)kMLP * kD * 2));
  short* w2T   = (short*)(ws + alloc((size_t)kD * kMLP * 2));
  short* Qb    = (short*)(ws + alloc((size_t)kTOK * kD * 2));
  short* Kb    = (short*)(ws + alloc((size_t)kTOK * kD * 2));
  short* Vb    = (short*)(ws + alloc((size_t)kTOK * kD * 2));
  short* hbuf  = (short*)(ws + alloc((size_t)kMPAD * kD * 2));
  short* gbuf  = (short*)(ws + alloc((size_t)kMPAD * kMLP * 2));

  // kTOK/8 = 2308 LN blocks + 576 + 576 + 288 pack blocks = 3748
  ln_prep<<<kTOK / 8 + 1440, 512, 0, stream>>>(
      x, ln1_g, ln1_b, xn, W1, W2, Wq, Wk, Wv, w1T, w2T, wqkvT);
  qkv_gemm<<<dim3((kTOK + 127) / 128, kH), 384, 0, stream>>>(
      xn, wqkvT, bq, bk, bv, Qb, Kb, Vb);
  attn_kernel<<<5 * kH * kB, 256, 0, stream>>>(Qb, Kb, Vb, x, out);
  ln_kernel<<<kTOK / 8, 512, 0, stream>>>(out, ln2_g, ln2_b, hbuf);
  gemm_bb<<<(kMPAD / 256) * (kMLP / 128), 512, 0, stream>>>(
      hbuf, w1T, b1, gbuf, nullptr, kTOK, kMLP, kD, 0);
  gemm2b<<<(kMPAD / 128) * (kD / 128), 256, 0, stream>>>(
      gbuf, w2T, b2, out, kTOK, kD, kMLP);
}